// Round 4
// baseline (884.378 us; speedup 1.0000x reference)
//
#include <hip/hip_runtime.h>
#include <stdint.h>

#define B_ 2
#define S_ 1024
#define D_ 768
#define H_ 12
#define DH 64
#define G_ 4
#define DG 192
#define T_ 2047
#define SCALEF 0.125f

typedef unsigned short u16;
typedef unsigned int u32;

__device__ __forceinline__ float uas(u32 x){ union { u32 i; float f; } v; v.i = x; return v.f; }
__device__ __forceinline__ float bf2f(u16 u){ return uas(((u32)u) << 16); }
__device__ __forceinline__ u16 f2bf(float f){
    union { float f; u32 i; } v; v.f = f;
    u32 x = v.i;
    u32 r = (x + 0x7fffu + ((x >> 16) & 1u)) >> 16;  // RNE
    return (u16)r;
}

// ---------------- Kernel A: grouped q/k/v projections (fp32 in, bf16 ws out) ----------------
__global__ __launch_bounds__(256) void proj_kernel(
    const float* __restrict__ query, const float* __restrict__ Wq,
    const float* __restrict__ Wk, const float* __restrict__ bk,
    const float* __restrict__ Wv, const float* __restrict__ bv,
    u16* __restrict__ qq, u16* __restrict__ ko, u16* __restrict__ vo)
{
    __shared__ float xs[D_][8];
    int tid = threadIdx.x;
    int rowg0 = blockIdx.x * 8;
    for (int idx = tid; idx < 8 * D_; idx += 256) {
        int r = idx / D_, e = idx % D_;
        xs[e][r] = query[(size_t)(rowg0 + r) * D_ + e];
    }
    __syncthreads();
    for (int cc = 0; cc < 3; cc++) {
        int c = tid + cc * 256;
        int g = c / DG, co = c % DG;
        size_t wbase = (size_t)(g*DG)*DG + co;
        float aq[8], ak[8], avv[8];
        #pragma unroll
        for (int r = 0; r < 8; r++) { aq[r]=0.f; ak[r]=0.f; avv[r]=0.f; }
        const float* xbase = &xs[g*DG][0];
        for (int ci = 0; ci < DG; ci++) {
            float wqv = Wq[wbase + (size_t)ci*DG];
            float wkv = Wk[wbase + (size_t)ci*DG];
            float wvv = Wv[wbase + (size_t)ci*DG];
            const float* xr = xbase + ci*8;
            #pragma unroll
            for (int r = 0; r < 8; r++) {
                float x = xr[r];
                aq[r] += x * wqv; ak[r] += x * wkv; avv[r] += x * wvv;
            }
        }
        int n = c / DH, d = c % DH;
        float bkv  = bk[c];
        float bvv2 = bv[c];
        #pragma unroll
        for (int r = 0; r < 8; r++) {
            int rowg = rowg0 + r;
            int b = rowg >> 10, s = rowg & 1023;
            size_t o = ((size_t)(b*H_ + n)*S_ + s)*DH + d;
            qq[o] = f2bf(aq[r]*SCALEF);
            ko[o] = f2bf(ak[r] + bkv);
            vo[o] = f2bf(avv[r] + bvv2);
        }
    }
}

// ---------------- Kernel B: r_head = position_embeds @ r_kernel ----------------
__global__ __launch_bounds__(256) void rhead_kernel(
    const float* __restrict__ pe, const float* __restrict__ rk,
    u16* __restrict__ R)
{
    __shared__ float xs[D_][8];
    int tid = threadIdx.x;
    int t0 = blockIdx.x * 8;
    for (int idx = tid; idx < 8 * D_; idx += 256) {
        int r = idx / D_, e = idx % D_;
        int t = t0 + r;
        xs[e][r] = (t < T_) ? pe[(size_t)t * D_ + e] : 0.0f;
    }
    __syncthreads();
    for (int cc = 0; cc < 3; cc++) {
        int c = tid + cc*256;
        float acc[8];
        #pragma unroll
        for (int r = 0; r < 8; r++) acc[r] = 0.f;
        for (int ci = 0; ci < D_; ci++) {
            float w = rk[(size_t)ci*D_ + c];
            const float* xr = &xs[ci][0];
            #pragma unroll
            for (int r = 0; r < 8; r++) acc[r] += xr[r]*w;
        }
        #pragma unroll
        for (int r = 0; r < 8; r++) {
            int t = t0 + r;
            if (t < T_) R[((size_t)((c>>6)*T_) + t)*DH + (c&63)] = f2bf(acc[r]);
        }
    }
}

// ---------------- Kernel C: fused rel-attention ----------------
// Block = (b, n, 8 i-rows). Scores (content + shifted pos) -> softmax -> PV.
// pos_shifted[i][j] = qp[i] . R[1024 + j - i]; computed per shared t = 1017+jj-i0
// column sweep, scatter-added into sc[r][jj-7+r]. attn_vec written FP32 into d_out.
__global__ __launch_bounds__(256) void attn_kernel(
    const u16* __restrict__ qq,
    const u16* __restrict__ kk, const u16* __restrict__ vv,
    const u16* __restrict__ R,
    const float* __restrict__ rwb, const float* __restrict__ rrb,
    float* __restrict__ av)
{
    __shared__ float qct[DH][8];
    __shared__ float qpt[DH][8];
    __shared__ float sc[8][S_];
    __shared__ float vsb[32][DH];
    int tid = threadIdx.x;
    int blk = blockIdx.x;
    int bn = blk >> 7;            // 0..23
    int it = blk & 127;
    int b = bn / H_, n = bn % H_;
    int i0 = it * 8;
    size_t hbase = (size_t)bn * S_ * DH;

    for (int idx = tid; idx < 8*DH; idx += 256) {
        int r = idx >> 6, d = idx & 63;
        float qv = bf2f(qq[hbase + (size_t)(i0 + r)*DH + d]);
        qct[d][r] = qv + rwb[n*DH + d] * SCALEF;
        qpt[d][r] = qv + rrb[n*DH + d] * SCALEF;
    }
    __syncthreads();

    // Phase 1: content scores, 2 consecutive j per thread
    for (int step = 0; step < 2; step++) {
        int jA = 2*tid + step*512;
        const u16* kA = kk + hbase + (size_t)jA*DH;
        float accA[8], accB[8];
        #pragma unroll
        for (int r = 0; r < 8; r++) { accA[r]=0.f; accB[r]=0.f; }
        #pragma unroll 2
        for (int d8 = 0; d8 < 8; d8++) {
            uint4 pa = *(const uint4*)(kA + d8*8);
            uint4 pb = *(const uint4*)(kA + DH + d8*8);
            const u32* wa = (const u32*)&pa;
            const u32* wb = (const u32*)&pb;
            #pragma unroll
            for (int q_ = 0; q_ < 4; q_++) {
                float a0 = uas(wa[q_] << 16), a1 = uas(wa[q_] & 0xffff0000u);
                float b0 = uas(wb[q_] << 16), b1 = uas(wb[q_] & 0xffff0000u);
                const float* x0 = &qct[d8*8 + 2*q_][0];
                const float* x1 = &qct[d8*8 + 2*q_ + 1][0];
                #pragma unroll
                for (int r = 0; r < 8; r++) {
                    accA[r] += x0[r]*a0; accB[r] += x0[r]*b0;
                    accA[r] += x1[r]*a1; accB[r] += x1[r]*b1;
                }
            }
        }
        #pragma unroll
        for (int r = 0; r < 8; r++) { sc[r][jA] = accA[r]; sc[r][jA+1] = accB[r]; }
    }
    __syncthreads();

    // Phase 2: position scores (jj in [0,1030], t = 1017+jj-i0; rows clamped <=2046)
    for (int step = 0; step < 3; step++) {
        int jjA = 2*tid + step*512;
        if (jjA > 1030) continue;
        int tA = 1017 + jjA - i0;
        int rowA = (tA     <= 2046) ? tA     : 2046;
        int rowB = (tA + 1 <= 2046) ? tA + 1 : 2046;
        const u16* rA = R + ((size_t)n*T_ + rowA)*DH;
        const u16* rB = R + ((size_t)n*T_ + rowB)*DH;
        float accA[8], accB[8];
        #pragma unroll
        for (int r = 0; r < 8; r++) { accA[r]=0.f; accB[r]=0.f; }
        #pragma unroll 2
        for (int d8 = 0; d8 < 8; d8++) {
            uint4 pa = *(const uint4*)(rA + d8*8);
            uint4 pb = *(const uint4*)(rB + d8*8);
            const u32* wa = (const u32*)&pa;
            const u32* wb = (const u32*)&pb;
            #pragma unroll
            for (int q_ = 0; q_ < 4; q_++) {
                float a0 = uas(wa[q_] << 16), a1 = uas(wa[q_] & 0xffff0000u);
                float b0 = uas(wb[q_] << 16), b1 = uas(wb[q_] & 0xffff0000u);
                const float* x0 = &qpt[d8*8 + 2*q_][0];
                const float* x1 = &qpt[d8*8 + 2*q_ + 1][0];
                #pragma unroll
                for (int r = 0; r < 8; r++) {
                    accA[r] += x0[r]*a0; accB[r] += x0[r]*b0;
                    accA[r] += x1[r]*a1; accB[r] += x1[r]*b1;
                }
            }
        }
        bool okA = (tA <= 2046);
        bool okB = (tA + 1 <= 2046) && (jjA + 1 <= 1030);
        #pragma unroll
        for (int r = 0; r < 8; r++) {
            int jx = jjA - 7 + r;
            if (okA && jx >= 0 && jx < S_) sc[r][jx] += accA[r];
            int jy = jx + 1;
            if (okB && jy >= 0 && jy < S_) sc[r][jy] += accB[r];
        }
    }
    __syncthreads();

    // Phase 3: HF rel_shift wraparound: (i=0, j=1023) uses qp row 1, R row 0
    if (i0 == 0 && tid == 0) {
        float sdot = 0.f;
        const u16* r0p = R + (size_t)n*T_*DH;
        for (int d = 0; d < DH; d++) sdot += qpt[d][1] * bf2f(r0p[d]);
        sc[0][1023] += sdot;
    }
    __syncthreads();

    // Phase 4: softmax per row (2 rows per wave)
    int wave = tid >> 6, lane = tid & 63;
    int r0 = wave*2, r1 = r0 + 1;
    float linv[2];
    for (int rr = 0; rr < 2; rr++) {
        int r = r0 + rr;
        float m = -1e30f;
        for (int kq = 0; kq < 16; kq++) m = fmaxf(m, sc[r][lane + kq*64]);
        #pragma unroll
        for (int off = 32; off; off >>= 1) m = fmaxf(m, __shfl_xor(m, off));
        float ssum = 0.f;
        for (int kq = 0; kq < 16; kq++) {
            int j = lane + kq*64;
            float p = __expf(sc[r][j] - m);
            sc[r][j] = p;
            ssum += p;
        }
        #pragma unroll
        for (int off = 32; off; off >>= 1) ssum += __shfl_xor(ssum, off);
        linv[rr] = 1.0f / ssum;
    }

    // Phase 5: PV with LDS-staged V tiles
    float O0 = 0.f, O1 = 0.f;
    for (int jt = 0; jt < 32; jt++) {
        __syncthreads();
        for (int idx = tid; idx < 32*DH; idx += 256) {
            int rj = idx >> 6, d = idx & 63;
            vsb[rj][d] = bf2f(vv[hbase + (size_t)(jt*32 + rj)*DH + d]);
        }
        __syncthreads();
        #pragma unroll 4
        for (int jj = 0; jj < 32; jj += 2) {
            float2 p0 = *(const float2*)&sc[r0][jt*32 + jj];
            float2 p1 = *(const float2*)&sc[r1][jt*32 + jj];
            float v0 = vsb[jj][lane];
            float v1 = vsb[jj+1][lane];
            O0 += p0.x*v0 + p0.y*v1;
            O1 += p1.x*v0 + p1.y*v1;
        }
    }

    // Phase 6: write attn_vec [B,S,768] FP32 into d_out (scratch use)
    size_t o0 = ((size_t)(b*S_) + i0 + r0)*D_ + n*DH + lane;
    av[o0]       = O0 * linv[0];
    av[o0 + D_]  = O1 * linv[1];
}

// ---------------- Kernel D: attn_vec @ Wo + bo, residual, LayerNorm (fp32 out) ----------------
// avi and out ALIAS (both d_out): each block reads only its own 8 rows into LDS
// before writing those same rows -> safe. No __restrict__ on avi/out.
__global__ __launch_bounds__(256) void out_kernel(
    const float* avi, const float* __restrict__ Wo,
    const float* __restrict__ bo, const float* __restrict__ query,
    const float* __restrict__ gamma, const float* __restrict__ beta,
    float* out)
{
    __shared__ float xs[D_][8];
    __shared__ float hb[8][D_];
    int tid = threadIdx.x;
    int rowg0 = blockIdx.x * 8;
    for (int idx = tid; idx < 8*D_; idx += 256) {
        int r = idx / D_, e = idx % D_;
        xs[e][r] = avi[(size_t)(rowg0 + r)*D_ + e];
    }
    __syncthreads();
    for (int cc = 0; cc < 3; cc++) {
        int c = tid + cc*256;
        float acc[8];
        #pragma unroll
        for (int r = 0; r < 8; r++) acc[r] = 0.f;
        for (int k = 0; k < D_; k++) {
            float w = Wo[(size_t)k*D_ + c];
            const float* xr = &xs[k][0];
            #pragma unroll
            for (int r = 0; r < 8; r++) acc[r] += xr[r]*w;
        }
        float bov = bo[c];
        #pragma unroll
        for (int r = 0; r < 8; r++) {
            hb[r][c] = acc[r] + bov + query[(size_t)(rowg0+r)*D_ + c];
        }
    }
    __syncthreads();
    int wave = tid >> 6, lane = tid & 63;
    for (int rr = 0; rr < 2; rr++) {
        int r = wave*2 + rr;
        float s = 0.f;
        for (int kq = 0; kq < 12; kq++) s += hb[r][lane + kq*64];
        #pragma unroll
        for (int off = 32; off; off >>= 1) s += __shfl_xor(s, off);
        float mu = s * (1.0f/768.0f);
        float vsum = 0.f;
        for (int kq = 0; kq < 12; kq++) { float d = hb[r][lane + kq*64] - mu; vsum += d*d; }
        #pragma unroll
        for (int off = 32; off; off >>= 1) vsum += __shfl_xor(vsum, off);
        float rstd = rsqrtf(vsum * (1.0f/768.0f) + 1e-9f);
        for (int kq = 0; kq < 12; kq++) {
            int c = lane + kq*64;
            out[(size_t)(rowg0+r)*D_ + c] = (hb[r][c] - mu)*rstd*gamma[c] + beta[c];
        }
    }
}

extern "C" void kernel_launch(void* const* d_in, const int* in_sizes, int n_in,
                              void* d_out, int out_size, void* d_ws, size_t ws_size,
                              hipStream_t stream) {
    const float* query = (const float*)d_in[0];
    const float* pe    = (const float*)d_in[1];
    const float* Wq    = (const float*)d_in[2];
    const float* Wk    = (const float*)d_in[3];
    const float* bk    = (const float*)d_in[4];
    const float* Wv    = (const float*)d_in[5];
    const float* bv    = (const float*)d_in[6];
    const float* rk    = (const float*)d_in[7];
    const float* rwb   = (const float*)d_in[8];
    const float* rrb   = (const float*)d_in[9];
    const float* Wo    = (const float*)d_in[10];
    const float* bo    = (const float*)d_in[11];
    const float* gamma = (const float*)d_in[12];
    const float* beta  = (const float*)d_in[13];
    float* out = (float*)d_out;

    u16* ws = (u16*)d_ws;
    const size_t SEG = (size_t)B_*H_*S_*DH;       // 1,572,864 elems (3 MB bf16)
    u16* qq = ws;             // [B,H,S,DH]
    u16* kk = qq + SEG;       // [B,H,S,DH]
    u16* vv = kk + SEG;       // [B,H,S,DH]
    u16* R  = vv + SEG;       // [H,2047,DH]
    float* av = out;          // attn_vec scratch lives in d_out (fp32)

    proj_kernel<<<256, 256, 0, stream>>>(query, Wq, Wk, bk, Wv, bv, qq, kk, vv);
    rhead_kernel<<<256, 256, 0, stream>>>(pe, rk, R);
    attn_kernel<<<3072, 256, 0, stream>>>(qq, kk, vv, R, rwb, rrb, av);
    out_kernel<<<256, 256, 0, stream>>>(av, Wo, bo, query, gamma, beta, out);
}

// Round 5
// 503.464 us; speedup vs baseline: 1.7566x; 1.7566x over previous
//
#include <hip/hip_runtime.h>
#include <stdint.h>

#define B_ 2
#define S_ 1024
#define D_ 768
#define H_ 12
#define DH 64
#define G_ 4
#define DG 192
#define T_ 2047
#define SCALEF 0.125f

typedef unsigned short u16;
typedef unsigned int u32;
typedef __attribute__((ext_vector_type(8))) short short8;
typedef __attribute__((ext_vector_type(4))) float floatx4;

__device__ __forceinline__ float uas(u32 x){ union { u32 i; float f; } v; v.i = x; return v.f; }
__device__ __forceinline__ float bf2f(u16 u){ return uas(((u32)u) << 16); }
__device__ __forceinline__ u16 f2bf(float f){
    union { float f; u32 i; } v; v.f = f;
    u32 x = v.i;
    u32 r = (x + 0x7fffu + ((x >> 16) & 1u)) >> 16;  // RNE
    return (u16)r;
}

// ---------------- Kernel A: grouped q/k/v projections (fp32 in, bf16 ws out) ----------------
// V is written TRANSPOSED: vt[(bn*DH + d)*S + s] for MFMA B-fragment loads in attn.
__global__ __launch_bounds__(256) void proj_kernel(
    const float* __restrict__ query, const float* __restrict__ Wq,
    const float* __restrict__ Wk, const float* __restrict__ bk,
    const float* __restrict__ Wv, const float* __restrict__ bv,
    u16* __restrict__ qq, u16* __restrict__ ko, u16* __restrict__ vt)
{
    __shared__ float xs[D_][8];
    int tid = threadIdx.x;
    int rowg0 = blockIdx.x * 8;
    for (int idx = tid; idx < 8 * D_; idx += 256) {
        int r = idx / D_, e = idx % D_;
        xs[e][r] = query[(size_t)(rowg0 + r) * D_ + e];
    }
    __syncthreads();
    for (int cc = 0; cc < 3; cc++) {
        int c = tid + cc * 256;
        int g = c / DG, co = c % DG;
        size_t wbase = (size_t)(g*DG)*DG + co;
        float aq[8], ak[8], avv[8];
        #pragma unroll
        for (int r = 0; r < 8; r++) { aq[r]=0.f; ak[r]=0.f; avv[r]=0.f; }
        const float* xbase = &xs[g*DG][0];
        for (int ci = 0; ci < DG; ci++) {
            float wqv = Wq[wbase + (size_t)ci*DG];
            float wkv = Wk[wbase + (size_t)ci*DG];
            float wvv = Wv[wbase + (size_t)ci*DG];
            const float* xr = xbase + ci*8;
            #pragma unroll
            for (int r = 0; r < 8; r++) {
                float x = xr[r];
                aq[r] += x * wqv; ak[r] += x * wkv; avv[r] += x * wvv;
            }
        }
        int n = c / DH, d = c % DH;
        float bkv  = bk[c];
        float bvv2 = bv[c];
        #pragma unroll
        for (int r = 0; r < 8; r++) {
            int rowg = rowg0 + r;
            int b = rowg >> 10, s = rowg & 1023;
            int bn = b*H_ + n;
            size_t o = ((size_t)bn*S_ + s)*DH + d;
            qq[o] = f2bf(aq[r]*SCALEF);
            ko[o] = f2bf(ak[r] + bkv);
            vt[((size_t)bn*DH + d)*S_ + s] = f2bf(avv[r] + bvv2);
        }
    }
}

// ---------------- Kernel B: r_head = position_embeds @ r_kernel ----------------
__global__ __launch_bounds__(256) void rhead_kernel(
    const float* __restrict__ pe, const float* __restrict__ rk,
    u16* __restrict__ R)
{
    __shared__ float xs[D_][8];
    int tid = threadIdx.x;
    int t0 = blockIdx.x * 8;
    for (int idx = tid; idx < 8 * D_; idx += 256) {
        int r = idx / D_, e = idx % D_;
        int t = t0 + r;
        xs[e][r] = (t < T_) ? pe[(size_t)t * D_ + e] : 0.0f;
    }
    __syncthreads();
    for (int cc = 0; cc < 3; cc++) {
        int c = tid + cc*256;
        float acc[8];
        #pragma unroll
        for (int r = 0; r < 8; r++) acc[r] = 0.f;
        for (int ci = 0; ci < D_; ci++) {
            float w = rk[(size_t)ci*D_ + c];
            const float* xr = &xs[ci][0];
            #pragma unroll
            for (int r = 0; r < 8; r++) acc[r] += xr[r]*w;
        }
        #pragma unroll
        for (int r = 0; r < 8; r++) {
            int t = t0 + r;
            if (t < T_) R[((size_t)((c>>6)*T_) + t)*DH + (c&63)] = f2bf(acc[r]);
        }
    }
}

// ---------------- Kernel C: MFMA fused rel-attention ----------------
// Block = one head (bn) x 16 i-rows. 4 waves.
// Content: S[i][j] tiles via mfma_f32_16x16x32_bf16 (A=q frag, B=K^T frag).
// Pos: PP[i][u] = qp[i].R[u] over the 65-tile u-band, scatter-add j=u+i-1024.
// Softmax per row in registers; probs repacked bf16 in-place (XOR chunk swizzle).
// PV: waves own 16-wide d-slices, B-frags from transposed vt.
__global__ __launch_bounds__(256) void attn_kernel(
    const u16* __restrict__ qq,
    const u16* __restrict__ kk, const u16* __restrict__ vt,
    const u16* __restrict__ R,
    const float* __restrict__ rwb, const float* __restrict__ rrb,
    float* __restrict__ av)
{
    __shared__ char smem[16*4096];   // 64 KB: sc rows fp32, later prob rows bf16
    int tid  = threadIdx.x;
    int wave = tid >> 6, lane = tid & 63;
    int qm   = lane & 15;            // m (or n) index within MFMA tile
    int quad = lane >> 4;            // 0..3
    int k8   = quad * 8;             // k-offset within K=32 slice
    int blk = blockIdx.x;
    int bn = blk >> 6;               // 0..23
    int it = blk & 63;
    int b = bn / H_, n = bn % H_;
    int i0 = it * 16;
    size_t hbase = (size_t)bn * S_ * DH;

    // ---- Q fragments (same in all waves): rows i0+qm, k = s*32 + k8 + j ----
    short8 qcf[2], qpf[2];
    #pragma unroll
    for (int s = 0; s < 2; s++) {
        const u16* qptr = qq + hbase + (size_t)(i0 + qm)*DH + s*32 + k8;
        const float* rwp = rwb + n*DH + s*32 + k8;
        const float* rrp = rrb + n*DH + s*32 + k8;
        #pragma unroll
        for (int j = 0; j < 8; j++) {
            float qv = bf2f(qptr[j]);
            qcf[s][j] = (short)f2bf(qv + rwp[j]*SCALEF);
            qpf[s][j] = (short)f2bf(qv + rrp[j]*SCALEF);
        }
    }

    // ---- Phase 1: content scores ----
    for (int tjt = 0; tjt < 16; tjt++) {
        int j0 = (wave*16 + tjt) * 16;
        const u16* kp = kk + hbase + (size_t)(j0 + qm)*DH + k8;
        short8 b0 = *(const short8*)(kp);
        short8 b1 = *(const short8*)(kp + 32);
        floatx4 acc = {0.f,0.f,0.f,0.f};
        acc = __builtin_amdgcn_mfma_f32_16x16x32_bf16(qcf[0], b0, acc, 0,0,0);
        acc = __builtin_amdgcn_mfma_f32_16x16x32_bf16(qcf[1], b1, acc, 0,0,0);
        #pragma unroll
        for (int g = 0; g < 4; g++) {
            ((float*)(smem + (quad*4 + g)*4096))[j0 + qm] = acc[g];
        }
    }
    __syncthreads();

    // ---- Phase 2: position scores over u-band [1008-i0 .. 2047-i0], 65 tiles ----
    int ubase = 1008 - i0;
    for (int m = wave; m < 65; m += 4) {
        int u0 = ubase + m*16;
        int uu = u0 + qm;                      // true u (= t)
        int ur = (uu <= 2046) ? uu : 2046;     // clamped load row
        const u16* rp = R + ((size_t)n*T_ + ur)*DH + k8;
        short8 b0 = *(const short8*)(rp);
        short8 b1 = *(const short8*)(rp + 32);
        floatx4 acc = {0.f,0.f,0.f,0.f};
        acc = __builtin_amdgcn_mfma_f32_16x16x32_bf16(qpf[0], b0, acc, 0,0,0);
        acc = __builtin_amdgcn_mfma_f32_16x16x32_bf16(qpf[1], b1, acc, 0,0,0);
        #pragma unroll
        for (int g = 0; g < 4; g++) {
            int row = quad*4 + g;
            int j = uu + i0 + row - 1024;
            if (j >= 0 && j < S_ && uu <= 2046)
                ((float*)(smem + row*4096))[j] += acc[g];
        }
    }
    // HF rel_shift wraparound: (i=0, j=1023) uses qp row 1, R row 0
    if (i0 == 0 && tid == 0) {
        float sdot = 0.f;
        const u16* r0p = R + (size_t)n*T_*DH;
        const u16* q1p = qq + hbase + DH;      // q row 1
        for (int d = 0; d < DH; d++)
            sdot += (bf2f(q1p[d]) + rrb[n*DH + d]*SCALEF) * bf2f(r0p[d]);
        ((float*)smem)[1023] += sdot;
    }
    __syncthreads();

    // ---- Phase 3: softmax per row; write normalized probs bf16 (swizzled chunks) ----
    // prob byte(r,j) = r*4096 + (((j>>3) ^ (r&7))<<4) + (j&7)*2
    for (int rr = 0; rr < 4; rr++) {
        int r = wave*4 + rr;
        const float* row = (const float*)(smem + r*4096);
        float p[16];
        float mx = -1e30f;
        #pragma unroll
        for (int q = 0; q < 16; q++) { p[q] = row[q*64 + lane]; mx = fmaxf(mx, p[q]); }
        #pragma unroll
        for (int off = 32; off; off >>= 1) mx = fmaxf(mx, __shfl_xor(mx, off));
        float ssum = 0.f;
        #pragma unroll
        for (int q = 0; q < 16; q++) { p[q] = __expf(p[q] - mx); ssum += p[q]; }
        #pragma unroll
        for (int off = 32; off; off >>= 1) ssum += __shfl_xor(ssum, off);
        float inv = 1.0f / ssum;
        int swz = r & 7;
        #pragma unroll
        for (int q = 0; q < 16; q++) {
            int j = q*64 + lane;
            u16* dst = (u16*)(smem + r*4096 + (((j >> 3) ^ swz) << 4) + (j & 7)*2);
            *dst = f2bf(p[q]*inv);
        }
    }
    __syncthreads();

    // ---- Phase 4: PV. wave owns d in [wave*16, wave*16+16) ----
    int d0 = wave*16;
    const u16* vbase = vt + ((size_t)bn*DH + d0 + qm)*S_;
    floatx4 o = {0.f,0.f,0.f,0.f};
    int aswz = qm & 7;
    for (int kt = 0; kt < 32; kt++) {
        int chunk = (kt*4 + quad) ^ aswz;     // (k/8) swizzled
        short8 a = *(const short8*)(smem + qm*4096 + (chunk << 4));
        short8 bfr = *(const short8*)(vbase + kt*32 + k8);
        o = __builtin_amdgcn_mfma_f32_16x16x32_bf16(a, bfr, o, 0,0,0);
    }
    #pragma unroll
    for (int g = 0; g < 4; g++) {
        int row = quad*4 + g;
        av[((size_t)(b*S_) + i0 + row)*D_ + n*DH + d0 + qm] = o[g];
    }
}

// ---------------- Kernel D: attn_vec @ Wo + bo, residual, LayerNorm (fp32 out) ----------------
// avi and out ALIAS (both d_out): each block reads only its own 8 rows into LDS
// before writing those same rows -> safe. No __restrict__ on avi/out.
__global__ __launch_bounds__(256) void out_kernel(
    const float* avi, const float* __restrict__ Wo,
    const float* __restrict__ bo, const float* __restrict__ query,
    const float* __restrict__ gamma, const float* __restrict__ beta,
    float* out)
{
    __shared__ float xs[D_][8];
    __shared__ float hb[8][D_];
    int tid = threadIdx.x;
    int rowg0 = blockIdx.x * 8;
    for (int idx = tid; idx < 8*D_; idx += 256) {
        int r = idx / D_, e = idx % D_;
        xs[e][r] = avi[(size_t)(rowg0 + r)*D_ + e];
    }
    __syncthreads();
    for (int cc = 0; cc < 3; cc++) {
        int c = tid + cc*256;
        float acc[8];
        #pragma unroll
        for (int r = 0; r < 8; r++) acc[r] = 0.f;
        for (int k = 0; k < D_; k++) {
            float w = Wo[(size_t)k*D_ + c];
            const float* xr = &xs[k][0];
            #pragma unroll
            for (int r = 0; r < 8; r++) acc[r] += xr[r]*w;
        }
        float bov = bo[c];
        #pragma unroll
        for (int r = 0; r < 8; r++) {
            hb[r][c] = acc[r] + bov + query[(size_t)(rowg0+r)*D_ + c];
        }
    }
    __syncthreads();
    int wave = tid >> 6, lane = tid & 63;
    for (int rr = 0; rr < 2; rr++) {
        int r = wave*2 + rr;
        float s = 0.f;
        for (int kq = 0; kq < 12; kq++) s += hb[r][lane + kq*64];
        #pragma unroll
        for (int off = 32; off; off >>= 1) s += __shfl_xor(s, off);
        float mu = s * (1.0f/768.0f);
        float vsum = 0.f;
        for (int kq = 0; kq < 12; kq++) { float d = hb[r][lane + kq*64] - mu; vsum += d*d; }
        #pragma unroll
        for (int off = 32; off; off >>= 1) vsum += __shfl_xor(vsum, off);
        float rstd = rsqrtf(vsum * (1.0f/768.0f) + 1e-9f);
        for (int kq = 0; kq < 12; kq++) {
            int c = lane + kq*64;
            out[(size_t)(rowg0+r)*D_ + c] = (hb[r][c] - mu)*rstd*gamma[c] + beta[c];
        }
    }
}

extern "C" void kernel_launch(void* const* d_in, const int* in_sizes, int n_in,
                              void* d_out, int out_size, void* d_ws, size_t ws_size,
                              hipStream_t stream) {
    const float* query = (const float*)d_in[0];
    const float* pe    = (const float*)d_in[1];
    const float* Wq    = (const float*)d_in[2];
    const float* Wk    = (const float*)d_in[3];
    const float* bk    = (const float*)d_in[4];
    const float* Wv    = (const float*)d_in[5];
    const float* bv    = (const float*)d_in[6];
    const float* rk    = (const float*)d_in[7];
    const float* rwb   = (const float*)d_in[8];
    const float* rrb   = (const float*)d_in[9];
    const float* Wo    = (const float*)d_in[10];
    const float* bo    = (const float*)d_in[11];
    const float* gamma = (const float*)d_in[12];
    const float* beta  = (const float*)d_in[13];
    float* out = (float*)d_out;

    u16* ws = (u16*)d_ws;
    const size_t SEG = (size_t)B_*H_*S_*DH;       // 1,572,864 elems (3 MB bf16)
    u16* qq = ws;             // [bn][s][d]
    u16* kk = qq + SEG;       // [bn][s][d]
    u16* vt = kk + SEG;       // [bn][d][s]  (transposed V)
    u16* R  = vt + SEG;       // [n][2047][d]
    float* av = out;          // attn_vec scratch lives in d_out (fp32)

    proj_kernel<<<256, 256, 0, stream>>>(query, Wq, Wk, bk, Wv, bv, qq, kk, vt);
    rhead_kernel<<<256, 256, 0, stream>>>(pe, rk, R);
    attn_kernel<<<1536, 256, 0, stream>>>(qq, kk, vt, R, rwb, rrb, av);
    out_kernel<<<256, 256, 0, stream>>>(av, Wo, bo, query, gamma, beta, out);
}

// Round 6
// 292.153 us; speedup vs baseline: 3.0271x; 1.7233x over previous
//
#include <hip/hip_runtime.h>
#include <stdint.h>

#define B_ 2
#define S_ 1024
#define D_ 768
#define H_ 12
#define DH 64
#define G_ 4
#define DG 192
#define T_ 2047
#define SCALEF 0.125f

typedef unsigned short u16;
typedef unsigned int u32;
typedef __attribute__((ext_vector_type(8))) short short8;
typedef __attribute__((ext_vector_type(4))) float floatx4;

__device__ __forceinline__ float uas(u32 x){ union { u32 i; float f; } v; v.i = x; return v.f; }
__device__ __forceinline__ float bf2f(u16 u){ return uas(((u32)u) << 16); }
__device__ __forceinline__ u16 f2bf(float f){
    union { float f; u32 i; } v; v.f = f;
    u32 x = v.i;
    u32 r = (x + 0x7fffu + ((x >> 16) & 1u)) >> 16;  // RNE
    return (u16)r;
}

// ---------------- Kernel A: grouped q/k/v projections (fp32 in, bf16 ws out) ----------------
// V is written TRANSPOSED: vt[(bn*DH + d)*S + s] for MFMA B-fragment loads in attn.
__global__ __launch_bounds__(256) void proj_kernel(
    const float* __restrict__ query, const float* __restrict__ Wq,
    const float* __restrict__ Wk, const float* __restrict__ bk,
    const float* __restrict__ Wv, const float* __restrict__ bv,
    u16* __restrict__ qq, u16* __restrict__ ko, u16* __restrict__ vt)
{
    __shared__ float xs[D_][8];
    int tid = threadIdx.x;
    int rowg0 = blockIdx.x * 8;
    for (int idx = tid; idx < 8 * D_; idx += 256) {
        int r = idx / D_, e = idx % D_;
        xs[e][r] = query[(size_t)(rowg0 + r) * D_ + e];
    }
    __syncthreads();
    for (int cc = 0; cc < 3; cc++) {
        int c = tid + cc * 256;
        int g = c / DG, co = c % DG;
        size_t wbase = (size_t)(g*DG)*DG + co;
        float aq[8], ak[8], avv[8];
        #pragma unroll
        for (int r = 0; r < 8; r++) { aq[r]=0.f; ak[r]=0.f; avv[r]=0.f; }
        const float* xbase = &xs[g*DG][0];
        for (int ci = 0; ci < DG; ci++) {
            float wqv = Wq[wbase + (size_t)ci*DG];
            float wkv = Wk[wbase + (size_t)ci*DG];
            float wvv = Wv[wbase + (size_t)ci*DG];
            const float* xr = xbase + ci*8;
            #pragma unroll
            for (int r = 0; r < 8; r++) {
                float x = xr[r];
                aq[r] += x * wqv; ak[r] += x * wkv; avv[r] += x * wvv;
            }
        }
        int n = c / DH, d = c % DH;
        float bkv  = bk[c];
        float bvv2 = bv[c];
        #pragma unroll
        for (int r = 0; r < 8; r++) {
            int rowg = rowg0 + r;
            int b = rowg >> 10, s = rowg & 1023;
            int bn = b*H_ + n;
            size_t o = ((size_t)bn*S_ + s)*DH + d;
            qq[o] = f2bf(aq[r]*SCALEF);
            ko[o] = f2bf(ak[r] + bkv);
            vt[((size_t)bn*DH + d)*S_ + s] = f2bf(avv[r] + bvv2);
        }
    }
}

// ---------------- Shared MFMA GEMM: C[M,768] = A[M,768] @ W[768,768] ----------------
// BM=64, BN=64, BK=32. A fp32 or bf16 (ABF16); W fp32 converted during staging.
// Ws staged transposed [n][k] with row pad (36 u16) to break 64B-stride conflicts.
// EPI 0: store bf16 R[((c>>6)*T + t)*64 + (c&63)], guard t < Mvalid.
// EPI 1: store fp32 outf[row*768+c] = acc + bias[c] + resid[row*768+c].
template<int EPI, bool ABF16>
__global__ __launch_bounds__(256) void gemm_kernel(
    const void* __restrict__ A, const float* __restrict__ W,
    const float* __restrict__ bias, const float* __restrict__ resid,
    u16* __restrict__ outb, float* __restrict__ outf, int Mvalid)
{
    __shared__ u16 As[64][32];
    __shared__ u16 Ws[64][36];
    int tid  = threadIdx.x;
    int wave = tid >> 6, lane = tid & 63;
    int qm   = lane & 15;
    int quad = lane >> 4;
    int k8   = quad * 8;
    int m0 = blockIdx.x * 64;
    int n0 = blockIdx.y * 64;

    floatx4 acc[4];
    #pragma unroll
    for (int t = 0; t < 4; t++) acc[t] = (floatx4){0.f,0.f,0.f,0.f};

    for (int kt = 0; kt < 24; kt++) {
        int k0 = kt * 32;
        // stage A tile [64][32]
        #pragma unroll
        for (int p = 0; p < 8; p++) {
            int idx = p*256 + tid;
            int m = idx >> 5, k = idx & 31;
            int row = m0 + m;
            int rowc = (row < Mvalid) ? row : (Mvalid - 1);
            if (ABF16) As[m][k] = ((const u16*)A)[(size_t)rowc*D_ + k0 + k];
            else       As[m][k] = f2bf(((const float*)A)[(size_t)rowc*D_ + k0 + k]);
        }
        // stage W tile transposed [n][k]
        #pragma unroll
        for (int p = 0; p < 8; p++) {
            int k = p*4 + (tid >> 6);
            int n = tid & 63;
            Ws[n][k] = f2bf(W[(size_t)(k0 + k)*D_ + n0 + n]);
        }
        __syncthreads();
        short8 a = *(const short8*)&As[wave*16 + qm][k8];
        #pragma unroll
        for (int bt = 0; bt < 4; bt++) {
            short8 b = *(const short8*)&Ws[bt*16 + qm][k8];
            acc[bt] = __builtin_amdgcn_mfma_f32_16x16x32_bf16(a, b, acc[bt], 0,0,0);
        }
        __syncthreads();
    }

    #pragma unroll
    for (int bt = 0; bt < 4; bt++) {
        int c = n0 + bt*16 + qm;
        #pragma unroll
        for (int g = 0; g < 4; g++) {
            int row = m0 + wave*16 + quad*4 + g;
            if (EPI == 0) {
                if (row < Mvalid)
                    outb[((size_t)(c >> 6)*T_ + row)*DH + (c & 63)] = f2bf(acc[bt][g]);
            } else {
                outf[(size_t)row*D_ + c] = acc[bt][g] + bias[c] + resid[(size_t)row*D_ + c];
            }
        }
    }
}

// ---------------- Kernel C: MFMA fused rel-attention ----------------
// Block = one head (bn) x 16 i-rows. 4 waves. attn_vec written BF16 into ws (av).
__global__ __launch_bounds__(256) void attn_kernel(
    const u16* __restrict__ qq,
    const u16* __restrict__ kk, const u16* __restrict__ vt,
    const u16* __restrict__ R,
    const float* __restrict__ rwb, const float* __restrict__ rrb,
    u16* __restrict__ av)
{
    __shared__ char smem[16*4096];   // 64 KB: sc rows fp32, later prob rows bf16
    int tid  = threadIdx.x;
    int wave = tid >> 6, lane = tid & 63;
    int qm   = lane & 15;
    int quad = lane >> 4;
    int k8   = quad * 8;
    int blk = blockIdx.x;
    int bn = blk >> 6;               // 0..23
    int it = blk & 63;
    int b = bn / H_, n = bn % H_;
    int i0 = it * 16;
    size_t hbase = (size_t)bn * S_ * DH;

    // ---- Q fragments ----
    short8 qcf[2], qpf[2];
    #pragma unroll
    for (int s = 0; s < 2; s++) {
        const u16* qptr = qq + hbase + (size_t)(i0 + qm)*DH + s*32 + k8;
        const float* rwp = rwb + n*DH + s*32 + k8;
        const float* rrp = rrb + n*DH + s*32 + k8;
        #pragma unroll
        for (int j = 0; j < 8; j++) {
            float qv = bf2f(qptr[j]);
            qcf[s][j] = (short)f2bf(qv + rwp[j]*SCALEF);
            qpf[s][j] = (short)f2bf(qv + rrp[j]*SCALEF);
        }
    }

    // ---- Phase 1: content scores ----
    for (int tjt = 0; tjt < 16; tjt++) {
        int j0 = (wave*16 + tjt) * 16;
        const u16* kp = kk + hbase + (size_t)(j0 + qm)*DH + k8;
        short8 b0 = *(const short8*)(kp);
        short8 b1 = *(const short8*)(kp + 32);
        floatx4 acc = {0.f,0.f,0.f,0.f};
        acc = __builtin_amdgcn_mfma_f32_16x16x32_bf16(qcf[0], b0, acc, 0,0,0);
        acc = __builtin_amdgcn_mfma_f32_16x16x32_bf16(qcf[1], b1, acc, 0,0,0);
        #pragma unroll
        for (int g = 0; g < 4; g++) {
            ((float*)(smem + (quad*4 + g)*4096))[j0 + qm] = acc[g];
        }
    }
    __syncthreads();

    // ---- Phase 2: position scores over u-band, 65 tiles ----
    int ubase = 1008 - i0;
    for (int m = wave; m < 65; m += 4) {
        int u0 = ubase + m*16;
        int uu = u0 + qm;
        int ur = (uu <= 2046) ? uu : 2046;
        const u16* rp = R + ((size_t)n*T_ + ur)*DH + k8;
        short8 b0 = *(const short8*)(rp);
        short8 b1 = *(const short8*)(rp + 32);
        floatx4 acc = {0.f,0.f,0.f,0.f};
        acc = __builtin_amdgcn_mfma_f32_16x16x32_bf16(qpf[0], b0, acc, 0,0,0);
        acc = __builtin_amdgcn_mfma_f32_16x16x32_bf16(qpf[1], b1, acc, 0,0,0);
        #pragma unroll
        for (int g = 0; g < 4; g++) {
            int row = quad*4 + g;
            int j = uu + i0 + row - 1024;
            if (j >= 0 && j < S_ && uu <= 2046)
                ((float*)(smem + row*4096))[j] += acc[g];
        }
    }
    // HF rel_shift wraparound: (i=0, j=1023) uses qp row 1, R row 0
    if (i0 == 0 && tid == 0) {
        float sdot = 0.f;
        const u16* r0p = R + (size_t)n*T_*DH;
        const u16* q1p = qq + hbase + DH;
        for (int d = 0; d < DH; d++)
            sdot += (bf2f(q1p[d]) + rrb[n*DH + d]*SCALEF) * bf2f(r0p[d]);
        ((float*)smem)[1023] += sdot;
    }
    __syncthreads();

    // ---- Phase 3: softmax; probs bf16, XOR chunk swizzle ----
    for (int rr = 0; rr < 4; rr++) {
        int r = wave*4 + rr;
        const float* row = (const float*)(smem + r*4096);
        float p[16];
        float mx = -1e30f;
        #pragma unroll
        for (int q = 0; q < 16; q++) { p[q] = row[q*64 + lane]; mx = fmaxf(mx, p[q]); }
        #pragma unroll
        for (int off = 32; off; off >>= 1) mx = fmaxf(mx, __shfl_xor(mx, off));
        float ssum = 0.f;
        #pragma unroll
        for (int q = 0; q < 16; q++) { p[q] = __expf(p[q] - mx); ssum += p[q]; }
        #pragma unroll
        for (int off = 32; off; off >>= 1) ssum += __shfl_xor(ssum, off);
        float inv = 1.0f / ssum;
        int swz = r & 7;
        #pragma unroll
        for (int q = 0; q < 16; q++) {
            int j = q*64 + lane;
            u16* dst = (u16*)(smem + r*4096 + (((j >> 3) ^ swz) << 4) + (j & 7)*2);
            *dst = f2bf(p[q]*inv);
        }
    }
    __syncthreads();

    // ---- Phase 4: PV; wave owns d-slice ----
    int d0 = wave*16;
    const u16* vbase = vt + ((size_t)bn*DH + d0 + qm)*S_;
    floatx4 o = {0.f,0.f,0.f,0.f};
    int aswz = qm & 7;
    for (int kt = 0; kt < 32; kt++) {
        int chunk = (kt*4 + quad) ^ aswz;
        short8 a = *(const short8*)(smem + qm*4096 + (chunk << 4));
        short8 bfr = *(const short8*)(vbase + kt*32 + k8);
        o = __builtin_amdgcn_mfma_f32_16x16x32_bf16(a, bfr, o, 0,0,0);
    }
    #pragma unroll
    for (int g = 0; g < 4; g++) {
        int row = quad*4 + g;
        av[((size_t)(b*S_) + i0 + row)*D_ + n*DH + d0 + qm] = f2bf(o[g]);
    }
}

// ---------------- Kernel E: in-place LayerNorm on d_out rows ----------------
// h (fp32) already = attn_out + bo + query. Per-block 8-row ownership -> alias-safe.
__global__ __launch_bounds__(256) void ln_kernel(
    const float* __restrict__ gamma, const float* __restrict__ beta,
    float* out)
{
    __shared__ float hb[8][D_];
    int tid = threadIdx.x;
    int rowg0 = blockIdx.x * 8;
    for (int idx = tid; idx < 8*D_; idx += 256) {
        int r = idx / D_, e = idx % D_;
        hb[r][e] = out[(size_t)(rowg0 + r)*D_ + e];
    }
    __syncthreads();
    int wave = tid >> 6, lane = tid & 63;
    for (int rr = 0; rr < 2; rr++) {
        int r = wave*2 + rr;
        float s = 0.f;
        for (int kq = 0; kq < 12; kq++) s += hb[r][lane + kq*64];
        #pragma unroll
        for (int off = 32; off; off >>= 1) s += __shfl_xor(s, off);
        float mu = s * (1.0f/768.0f);
        float vsum = 0.f;
        for (int kq = 0; kq < 12; kq++) { float d = hb[r][lane + kq*64] - mu; vsum += d*d; }
        #pragma unroll
        for (int off = 32; off; off >>= 1) vsum += __shfl_xor(vsum, off);
        float rstd = rsqrtf(vsum * (1.0f/768.0f) + 1e-9f);
        for (int kq = 0; kq < 12; kq++) {
            int c = lane + kq*64;
            out[(size_t)(rowg0+r)*D_ + c] = (hb[r][c] - mu)*rstd*gamma[c] + beta[c];
        }
    }
}

extern "C" void kernel_launch(void* const* d_in, const int* in_sizes, int n_in,
                              void* d_out, int out_size, void* d_ws, size_t ws_size,
                              hipStream_t stream) {
    const float* query = (const float*)d_in[0];
    const float* pe    = (const float*)d_in[1];
    const float* Wq    = (const float*)d_in[2];
    const float* Wk    = (const float*)d_in[3];
    const float* bk    = (const float*)d_in[4];
    const float* Wv    = (const float*)d_in[5];
    const float* bv    = (const float*)d_in[6];
    const float* rk    = (const float*)d_in[7];
    const float* rwb   = (const float*)d_in[8];
    const float* rrb   = (const float*)d_in[9];
    const float* Wo    = (const float*)d_in[10];
    const float* bo    = (const float*)d_in[11];
    const float* gamma = (const float*)d_in[12];
    const float* beta  = (const float*)d_in[13];
    float* out = (float*)d_out;

    u16* ws = (u16*)d_ws;
    const size_t SEG = (size_t)B_*H_*S_*DH;       // 1,572,864 elems (3 MB bf16)
    u16* qq = ws;             // [bn][s][d]
    u16* kk = qq + SEG;       // [bn][s][d]
    u16* vt = kk + SEG;       // [bn][d][s]  (transposed V)
    u16* R  = vt + SEG;       // [n][2047][d]
    u16* av = R + SEG;        // [b*S+s][n*64+d] bf16 attn_vec

    proj_kernel<<<256, 256, 0, stream>>>(query, Wq, Wk, bk, Wv, bv, qq, kk, vt);
    // r_head: pe[2047,768] @ rk[768,768] -> R (bf16, [n][t][d])
    gemm_kernel<0,false><<<dim3(32,12), 256, 0, stream>>>(pe, rk, nullptr, nullptr, R, nullptr, T_);
    attn_kernel<<<1536, 256, 0, stream>>>(qq, kk, vt, R, rwb, rrb, av);
    // h = av @ Wo + bo + query -> d_out (fp32)
    gemm_kernel<1,true><<<dim3(32,12), 256, 0, stream>>>(av, Wo, bo, query, nullptr, out, B_*S_);
    ln_kernel<<<256, 256, 0, stream>>>(gamma, beta, out);
}

// Round 7
// 232.632 us; speedup vs baseline: 3.8016x; 1.2559x over previous
//
#include <hip/hip_runtime.h>
#include <stdint.h>

#define B_ 2
#define S_ 1024
#define D_ 768
#define H_ 12
#define DH 64
#define G_ 4
#define DG 192
#define T_ 2047
#define SCALEF 0.125f

typedef unsigned short u16;
typedef unsigned int u32;
typedef __attribute__((ext_vector_type(8))) short short8;
typedef __attribute__((ext_vector_type(4))) float floatx4;

__device__ __forceinline__ float uas(u32 x){ union { u32 i; float f; } v; v.i = x; return v.f; }
__device__ __forceinline__ float bf2f(u16 u){ return uas(((u32)u) << 16); }
__device__ __forceinline__ u16 f2bf(float f){
    union { float f; u32 i; } v; v.f = f;
    u32 x = v.i;
    u32 r = (x + 0x7fffu + ((x >> 16) & 1u)) >> 16;  // RNE
    return (u16)r;
}

// ---------------- Kernel A: MFMA grouped q/k/v projections ----------------
// Block = (64-row m-tile, group g, 64-col n-tile). Computes q,k,v together:
// A (query slice) staged once; 3 W tiles staged transposed [n][k] pad 38.
// As padded to [64][40] -> conflict-free ds_read_b128 fragments.
__global__ __launch_bounds__(256) void proj_kernel(
    const float* __restrict__ query,
    const float* __restrict__ Wq, const float* __restrict__ Wk, const float* __restrict__ Wv,
    const float* __restrict__ bk, const float* __restrict__ bv,
    u16* __restrict__ qq, u16* __restrict__ ko, u16* __restrict__ vt)
{
    __shared__ u16 As[64][40];
    __shared__ u16 Ws[3][64][38];
    int tid  = threadIdx.x;
    int wave = tid >> 6, lane = tid & 63;
    int qm   = lane & 15;
    int quad = lane >> 4;
    int k8   = quad * 8;
    int m0 = blockIdx.x * 64;
    int g  = blockIdx.y / 3;
    int n0 = (blockIdx.y % 3) * 64;      // within group's 192 out cols

    const float* Wm[3] = { Wq, Wk, Wv };

    floatx4 acc[3][4];
    #pragma unroll
    for (int md = 0; md < 3; md++)
        #pragma unroll
        for (int bt = 0; bt < 4; bt++) acc[md][bt] = (floatx4){0.f,0.f,0.f,0.f};

    for (int kt = 0; kt < 6; kt++) {
        int k0 = kt * 32;
        // stage A: query[m0+m][g*192 + k0 + k]
        #pragma unroll
        for (int p = 0; p < 8; p++) {
            int idx = p*256 + tid;
            int m = idx >> 5, k = idx & 31;
            As[m][k] = f2bf(query[(size_t)(m0 + m)*D_ + g*DG + k0 + k]);
        }
        // stage W tiles transposed: Ws[md][n][k] = W[g][k0+k][n0+n]
        #pragma unroll
        for (int md = 0; md < 3; md++) {
            const float* W = Wm[md] + (size_t)g*DG*DG;
            #pragma unroll
            for (int p = 0; p < 8; p++) {
                int k = p*4 + (tid >> 6);
                int n = tid & 63;
                Ws[md][n][k] = f2bf(W[(size_t)(k0 + k)*DG + n0 + n]);
            }
        }
        __syncthreads();
        short8 a = *(const short8*)&As[wave*16 + qm][k8];
        #pragma unroll
        for (int md = 0; md < 3; md++) {
            #pragma unroll
            for (int bt = 0; bt < 4; bt++) {
                short8 b = *(const short8*)&Ws[md][bt*16 + qm][k8];
                acc[md][bt] = __builtin_amdgcn_mfma_f32_16x16x32_bf16(a, b, acc[md][bt], 0,0,0);
            }
        }
        __syncthreads();
    }

    // epilogue: c = g*192 + n0 + bt*16 + qm; rows rowbase..rowbase+3 (same b)
    int rowbase = m0 + wave*16 + quad*4;
    int b  = rowbase >> 10;
    int s0 = rowbase & 1023;
    #pragma unroll
    for (int bt = 0; bt < 4; bt++) {
        int c = g*DG + n0 + bt*16 + qm;
        int n = c >> 6, d = c & 63;
        int bn = b*H_ + n;
        float bkv = bk[c], bvv = bv[c];
        #pragma unroll
        for (int gg = 0; gg < 4; gg++) {
            size_t o = ((size_t)bn*S_ + s0 + gg)*DH + d;
            qq[o] = f2bf(acc[0][bt][gg]*SCALEF);
            ko[o] = f2bf(acc[1][bt][gg] + bkv);
        }
        union { u16 h[4]; uint2 v; } vv;
        #pragma unroll
        for (int gg = 0; gg < 4; gg++) vv.h[gg] = f2bf(acc[2][bt][gg] + bvv);
        *(uint2*)(vt + ((size_t)bn*DH + d)*S_ + s0) = vv.v;   // s0 % 4 == 0 -> 8B aligned
    }
}

// ---------------- Shared MFMA GEMM: C[M,768] = A[M,768] @ W[768,768] ----------------
// BM=64, BN=64, BK=32. A fp32 or bf16 (ABF16); W fp32 converted during staging.
// EPI 0: store bf16 R[((c>>6)*T + t)*64 + (c&63)], guard t < Mvalid.
// EPI 1: store fp32 outf[row*768+c] = acc + bias[c] + resid[row*768+c].
template<int EPI, bool ABF16>
__global__ __launch_bounds__(256) void gemm_kernel(
    const void* __restrict__ A, const float* __restrict__ W,
    const float* __restrict__ bias, const float* __restrict__ resid,
    u16* __restrict__ outb, float* __restrict__ outf, int Mvalid)
{
    __shared__ u16 As[64][32];
    __shared__ u16 Ws[64][36];
    int tid  = threadIdx.x;
    int wave = tid >> 6, lane = tid & 63;
    int qm   = lane & 15;
    int quad = lane >> 4;
    int k8   = quad * 8;
    int m0 = blockIdx.x * 64;
    int n0 = blockIdx.y * 64;

    floatx4 acc[4];
    #pragma unroll
    for (int t = 0; t < 4; t++) acc[t] = (floatx4){0.f,0.f,0.f,0.f};

    for (int kt = 0; kt < 24; kt++) {
        int k0 = kt * 32;
        #pragma unroll
        for (int p = 0; p < 8; p++) {
            int idx = p*256 + tid;
            int m = idx >> 5, k = idx & 31;
            int row = m0 + m;
            int rowc = (row < Mvalid) ? row : (Mvalid - 1);
            if (ABF16) As[m][k] = ((const u16*)A)[(size_t)rowc*D_ + k0 + k];
            else       As[m][k] = f2bf(((const float*)A)[(size_t)rowc*D_ + k0 + k]);
        }
        #pragma unroll
        for (int p = 0; p < 8; p++) {
            int k = p*4 + (tid >> 6);
            int n = tid & 63;
            Ws[n][k] = f2bf(W[(size_t)(k0 + k)*D_ + n0 + n]);
        }
        __syncthreads();
        short8 a = *(const short8*)&As[wave*16 + qm][k8];
        #pragma unroll
        for (int bt = 0; bt < 4; bt++) {
            short8 b = *(const short8*)&Ws[bt*16 + qm][k8];
            acc[bt] = __builtin_amdgcn_mfma_f32_16x16x32_bf16(a, b, acc[bt], 0,0,0);
        }
        __syncthreads();
    }

    #pragma unroll
    for (int bt = 0; bt < 4; bt++) {
        int c = n0 + bt*16 + qm;
        #pragma unroll
        for (int g = 0; g < 4; g++) {
            int row = m0 + wave*16 + quad*4 + g;
            if (EPI == 0) {
                if (row < Mvalid)
                    outb[((size_t)(c >> 6)*T_ + row)*DH + (c & 63)] = f2bf(acc[bt][g]);
            } else {
                outf[(size_t)row*D_ + c] = acc[bt][g] + bias[c] + resid[(size_t)row*D_ + c];
            }
        }
    }
}

// ---------------- Kernel C: MFMA fused rel-attention (bf16 score scratch) ----------------
// Block = one head (bn) x 16 i-rows. 4 waves. 32KB LDS -> 4 blocks/CU.
__global__ __launch_bounds__(256) void attn_kernel(
    const u16* __restrict__ qq,
    const u16* __restrict__ kk, const u16* __restrict__ vt,
    const u16* __restrict__ R,
    const float* __restrict__ rwb, const float* __restrict__ rrb,
    u16* __restrict__ av)
{
    __shared__ char smem[16*2048];   // 16 rows x 1024 bf16 scores / probs
    int tid  = threadIdx.x;
    int wave = tid >> 6, lane = tid & 63;
    int qm   = lane & 15;
    int quad = lane >> 4;
    int k8   = quad * 8;
    int blk = blockIdx.x;
    int bn = blk >> 6;               // 0..23
    int it = blk & 63;
    int b = bn / H_, n = bn % H_;
    int i0 = it * 16;
    size_t hbase = (size_t)bn * S_ * DH;

    // ---- Q fragments ----
    short8 qcf[2], qpf[2];
    #pragma unroll
    for (int s = 0; s < 2; s++) {
        const u16* qptr = qq + hbase + (size_t)(i0 + qm)*DH + s*32 + k8;
        const float* rwp = rwb + n*DH + s*32 + k8;
        const float* rrp = rrb + n*DH + s*32 + k8;
        #pragma unroll
        for (int j = 0; j < 8; j++) {
            float qv = bf2f(qptr[j]);
            qcf[s][j] = (short)f2bf(qv + rwp[j]*SCALEF);
            qpf[s][j] = (short)f2bf(qv + rrp[j]*SCALEF);
        }
    }

    // ---- Phase 1: content scores -> bf16 sc ----
    for (int tjt = 0; tjt < 16; tjt++) {
        int j0 = (wave*16 + tjt) * 16;
        const u16* kp = kk + hbase + (size_t)(j0 + qm)*DH + k8;
        short8 b0 = *(const short8*)(kp);
        short8 b1 = *(const short8*)(kp + 32);
        floatx4 acc = {0.f,0.f,0.f,0.f};
        acc = __builtin_amdgcn_mfma_f32_16x16x32_bf16(qcf[0], b0, acc, 0,0,0);
        acc = __builtin_amdgcn_mfma_f32_16x16x32_bf16(qcf[1], b1, acc, 0,0,0);
        #pragma unroll
        for (int g = 0; g < 4; g++) {
            ((u16*)(smem + (quad*4 + g)*2048))[j0 + qm] = f2bf(acc[g]);
        }
    }
    __syncthreads();

    // ---- Phase 2: position scores over u-band, 65 tiles; bf16 RMW (unique targets) ----
    int ubase = 1008 - i0;
    for (int m = wave; m < 65; m += 4) {
        int u0 = ubase + m*16;
        int uu = u0 + qm;
        int ur = (uu <= 2046) ? uu : 2046;
        const u16* rp = R + ((size_t)n*T_ + ur)*DH + k8;
        short8 b0 = *(const short8*)(rp);
        short8 b1 = *(const short8*)(rp + 32);
        floatx4 acc = {0.f,0.f,0.f,0.f};
        acc = __builtin_amdgcn_mfma_f32_16x16x32_bf16(qpf[0], b0, acc, 0,0,0);
        acc = __builtin_amdgcn_mfma_f32_16x16x32_bf16(qpf[1], b1, acc, 0,0,0);
        #pragma unroll
        for (int g = 0; g < 4; g++) {
            int row = quad*4 + g;
            int j = uu + i0 + row - 1024;
            if (j >= 0 && j < S_ && uu <= 2046) {
                u16* p = (u16*)(smem + row*2048) + j;
                *p = f2bf(bf2f(*p) + acc[g]);
            }
        }
    }
    // HF rel_shift wraparound: (i=0, j=1023) uses qp row 1, R row 0
    if (i0 == 0 && tid == 0) {
        float sdot = 0.f;
        const u16* r0p = R + (size_t)n*T_*DH;
        const u16* q1p = qq + hbase + DH;
        for (int d = 0; d < DH; d++)
            sdot += (bf2f(q1p[d]) + rrb[n*DH + d]*SCALEF) * bf2f(r0p[d]);
        u16* p = (u16*)smem + 1023;
        *p = f2bf(bf2f(*p) + sdot);
    }
    __syncthreads();

    // ---- Phase 3: softmax; probs bf16, XOR chunk swizzle ----
    for (int rr = 0; rr < 4; rr++) {
        int r = wave*4 + rr;
        const u16* row16 = (const u16*)(smem + r*2048);
        float p[16];
        float mx = -1e30f;
        #pragma unroll
        for (int q = 0; q < 16; q++) { p[q] = bf2f(row16[q*64 + lane]); mx = fmaxf(mx, p[q]); }
        #pragma unroll
        for (int off = 32; off; off >>= 1) mx = fmaxf(mx, __shfl_xor(mx, off));
        float ssum = 0.f;
        #pragma unroll
        for (int q = 0; q < 16; q++) { p[q] = __expf(p[q] - mx); ssum += p[q]; }
        #pragma unroll
        for (int off = 32; off; off >>= 1) ssum += __shfl_xor(ssum, off);
        float inv = 1.0f / ssum;
        int swz = r & 7;
        #pragma unroll
        for (int q = 0; q < 16; q++) {
            int j = q*64 + lane;
            u16* dst = (u16*)(smem + r*2048 + (((j >> 3) ^ swz) << 4) + (j & 7)*2);
            *dst = f2bf(p[q]*inv);
        }
    }
    __syncthreads();

    // ---- Phase 4: PV; wave owns d-slice ----
    int d0 = wave*16;
    const u16* vbase = vt + ((size_t)bn*DH + d0 + qm)*S_;
    floatx4 o = {0.f,0.f,0.f,0.f};
    int aswz = qm & 7;
    for (int kt = 0; kt < 32; kt++) {
        int chunk = (kt*4 + quad) ^ aswz;
        short8 a = *(const short8*)(smem + qm*2048 + (chunk << 4));
        short8 bfr = *(const short8*)(vbase + kt*32 + k8);
        o = __builtin_amdgcn_mfma_f32_16x16x32_bf16(a, bfr, o, 0,0,0);
    }
    #pragma unroll
    for (int g = 0; g < 4; g++) {
        int row = quad*4 + g;
        av[((size_t)(b*S_) + i0 + row)*D_ + n*DH + d0 + qm] = f2bf(o[g]);
    }
}

// ---------------- Kernel E: in-place LayerNorm on d_out rows ----------------
__global__ __launch_bounds__(256) void ln_kernel(
    const float* __restrict__ gamma, const float* __restrict__ beta,
    float* out)
{
    __shared__ float hb[8][D_];
    int tid = threadIdx.x;
    int rowg0 = blockIdx.x * 8;
    for (int idx = tid; idx < 8*D_; idx += 256) {
        int r = idx / D_, e = idx % D_;
        hb[r][e] = out[(size_t)(rowg0 + r)*D_ + e];
    }
    __syncthreads();
    int wave = tid >> 6, lane = tid & 63;
    for (int rr = 0; rr < 2; rr++) {
        int r = wave*2 + rr;
        float s = 0.f;
        for (int kq = 0; kq < 12; kq++) s += hb[r][lane + kq*64];
        #pragma unroll
        for (int off = 32; off; off >>= 1) s += __shfl_xor(s, off);
        float mu = s * (1.0f/768.0f);
        float vsum = 0.f;
        for (int kq = 0; kq < 12; kq++) { float d = hb[r][lane + kq*64] - mu; vsum += d*d; }
        #pragma unroll
        for (int off = 32; off; off >>= 1) vsum += __shfl_xor(vsum, off);
        float rstd = rsqrtf(vsum * (1.0f/768.0f) + 1e-9f);
        for (int kq = 0; kq < 12; kq++) {
            int c = lane + kq*64;
            out[(size_t)(rowg0+r)*D_ + c] = (hb[r][c] - mu)*rstd*gamma[c] + beta[c];
        }
    }
}

extern "C" void kernel_launch(void* const* d_in, const int* in_sizes, int n_in,
                              void* d_out, int out_size, void* d_ws, size_t ws_size,
                              hipStream_t stream) {
    const float* query = (const float*)d_in[0];
    const float* pe    = (const float*)d_in[1];
    const float* Wq    = (const float*)d_in[2];
    const float* Wk    = (const float*)d_in[3];
    const float* bk    = (const float*)d_in[4];
    const float* Wv    = (const float*)d_in[5];
    const float* bv    = (const float*)d_in[6];
    const float* rk    = (const float*)d_in[7];
    const float* rwb   = (const float*)d_in[8];
    const float* rrb   = (const float*)d_in[9];
    const float* Wo    = (const float*)d_in[10];
    const float* bo    = (const float*)d_in[11];
    const float* gamma = (const float*)d_in[12];
    const float* beta  = (const float*)d_in[13];
    float* out = (float*)d_out;

    u16* ws = (u16*)d_ws;
    const size_t SEG = (size_t)B_*H_*S_*DH;       // 1,572,864 elems (3 MB bf16)
    u16* qq = ws;             // [bn][s][d]
    u16* kk = qq + SEG;       // [bn][s][d]
    u16* vt = kk + SEG;       // [bn][d][s]  (transposed V)
    u16* R  = vt + SEG;       // [n][2047][d]
    u16* av = R + SEG;        // [b*S+s][n*64+d] bf16 attn_vec

    proj_kernel<<<dim3(32,12), 256, 0, stream>>>(query, Wq, Wk, Wv, bk, bv, qq, kk, vt);
    gemm_kernel<0,false><<<dim3(32,12), 256, 0, stream>>>(pe, rk, nullptr, nullptr, R, nullptr, T_);
    attn_kernel<<<1536, 256, 0, stream>>>(qq, kk, vt, R, rwb, rrb, av);
    gemm_kernel<1,true><<<dim3(32,12), 256, 0, stream>>>(av, Wo, bo, query, nullptr, out, B_*S_);
    ln_kernel<<<256, 256, 0, stream>>>(gamma, beta, out);
}

// Round 8
// 209.543 us; speedup vs baseline: 4.2205x; 1.1102x over previous
//
#include <hip/hip_runtime.h>
#include <stdint.h>

#define B_ 2
#define S_ 1024
#define D_ 768
#define H_ 12
#define DH 64
#define G_ 4
#define DG 192
#define T_ 2047
#define SCALEF 0.125f

typedef unsigned short u16;
typedef unsigned int u32;
typedef __attribute__((ext_vector_type(8))) short short8;
typedef __attribute__((ext_vector_type(4))) float floatx4;

__device__ __forceinline__ float uas(u32 x){ union { u32 i; float f; } v; v.i = x; return v.f; }
__device__ __forceinline__ float bf2f(u16 u){ return uas(((u32)u) << 16); }
__device__ __forceinline__ u16 f2bf(float f){
    union { float f; u32 i; } v; v.f = f;
    u32 x = v.i;
    u32 r = (x + 0x7fffu + ((x >> 16) & 1u)) >> 16;  // RNE
    return (u16)r;
}

// ---------------- Kernel A: MFMA grouped q/k/v projections ----------------
__global__ __launch_bounds__(256) void proj_kernel(
    const float* __restrict__ query,
    const float* __restrict__ Wq, const float* __restrict__ Wk, const float* __restrict__ Wv,
    const float* __restrict__ bk, const float* __restrict__ bv,
    u16* __restrict__ qq, u16* __restrict__ ko, u16* __restrict__ vt)
{
    __shared__ u16 As[64][40];
    __shared__ u16 Ws[3][64][38];
    int tid  = threadIdx.x;
    int wave = tid >> 6, lane = tid & 63;
    int qm   = lane & 15;
    int quad = lane >> 4;
    int k8   = quad * 8;
    int m0 = blockIdx.x * 64;
    int g  = blockIdx.y / 3;
    int n0 = (blockIdx.y % 3) * 64;

    const float* Wm[3] = { Wq, Wk, Wv };

    floatx4 acc[3][4];
    #pragma unroll
    for (int md = 0; md < 3; md++)
        #pragma unroll
        for (int bt = 0; bt < 4; bt++) acc[md][bt] = (floatx4){0.f,0.f,0.f,0.f};

    for (int kt = 0; kt < 6; kt++) {
        int k0 = kt * 32;
        #pragma unroll
        for (int p = 0; p < 8; p++) {
            int idx = p*256 + tid;
            int m = idx >> 5, k = idx & 31;
            As[m][k] = f2bf(query[(size_t)(m0 + m)*D_ + g*DG + k0 + k]);
        }
        #pragma unroll
        for (int md = 0; md < 3; md++) {
            const float* W = Wm[md] + (size_t)g*DG*DG;
            #pragma unroll
            for (int p = 0; p < 8; p++) {
                int k = p*4 + (tid >> 6);
                int n = tid & 63;
                Ws[md][n][k] = f2bf(W[(size_t)(k0 + k)*DG + n0 + n]);
            }
        }
        __syncthreads();
        short8 a = *(const short8*)&As[wave*16 + qm][k8];
        #pragma unroll
        for (int md = 0; md < 3; md++) {
            #pragma unroll
            for (int bt = 0; bt < 4; bt++) {
                short8 b = *(const short8*)&Ws[md][bt*16 + qm][k8];
                acc[md][bt] = __builtin_amdgcn_mfma_f32_16x16x32_bf16(a, b, acc[md][bt], 0,0,0);
            }
        }
        __syncthreads();
    }

    int rowbase = m0 + wave*16 + quad*4;
    int b  = rowbase >> 10;
    int s0 = rowbase & 1023;
    #pragma unroll
    for (int bt = 0; bt < 4; bt++) {
        int c = g*DG + n0 + bt*16 + qm;
        int n = c >> 6, d = c & 63;
        int bn = b*H_ + n;
        float bkv = bk[c], bvv = bv[c];
        #pragma unroll
        for (int gg = 0; gg < 4; gg++) {
            size_t o = ((size_t)bn*S_ + s0 + gg)*DH + d;
            qq[o] = f2bf(acc[0][bt][gg]*SCALEF);
            ko[o] = f2bf(acc[1][bt][gg] + bkv);
        }
        union { u16 h[4]; uint2 v; } vv;
        #pragma unroll
        for (int gg = 0; gg < 4; gg++) vv.h[gg] = f2bf(acc[2][bt][gg] + bvv);
        *(uint2*)(vt + ((size_t)bn*DH + d)*S_ + s0) = vv.v;
    }
}

// ---------------- Shared MFMA GEMM v2: BM=64 BN=32 BK=64, reg-prefetch pipeline ----
// EPI 0: store bf16 R[((c>>6)*T + row)*64 + (c&63)], guard row < Mvalid.
// EPI 1: store fp32 outf = acc + bias + resid.
template<int EPI, bool ABF16>
__global__ __launch_bounds__(256) void gemm_kernel(
    const void* __restrict__ A, const float* __restrict__ W,
    const float* __restrict__ bias, const float* __restrict__ resid,
    u16* __restrict__ outb, float* __restrict__ outf, int Mvalid)
{
    __shared__ u16 As[64][72];
    __shared__ u16 Ws[32][72];
    int tid  = threadIdx.x;
    int wave = tid >> 6, lane = tid & 63;
    int qm   = lane & 15;
    int quad = lane >> 4;
    int k8   = quad * 8;
    int m0 = blockIdx.x * 64;
    int n0 = blockIdx.y * 32;
    int wn = tid & 31, wk = tid >> 5;    // W staging: col n, k-octet

    float4 af[4]; short8 ab[2]; float wf[8];
    floatx4 acc[2];
    acc[0] = (floatx4){0.f,0.f,0.f,0.f};
    acc[1] = (floatx4){0.f,0.f,0.f,0.f};

    // prefetch k0 = 0
    if (ABF16) {
        #pragma unroll
        for (int p = 0; p < 2; p++) {
            int id = p*256 + tid; int m = id >> 3, kq = id & 7;
            ab[p] = *(const short8*)((const u16*)A + (size_t)(m0+m)*D_ + kq*8);
        }
    } else {
        #pragma unroll
        for (int p = 0; p < 4; p++) {
            int id = p*256 + tid; int m = id >> 4, kq = id & 15;
            int row = m0 + m; if (row >= Mvalid) row = Mvalid - 1;
            af[p] = *(const float4*)((const float*)A + (size_t)row*D_ + kq*4);
        }
    }
    #pragma unroll
    for (int p = 0; p < 8; p++) wf[p] = W[(size_t)(wk*8 + p)*D_ + n0 + wn];

    for (int kt = 0; kt < 12; kt++) {
        __syncthreads();
        // stage regs -> LDS
        if (ABF16) {
            #pragma unroll
            for (int p = 0; p < 2; p++) {
                int id = p*256 + tid; int m = id >> 3, kq = id & 7;
                *(short8*)&As[m][kq*8] = ab[p];
            }
        } else {
            #pragma unroll
            for (int p = 0; p < 4; p++) {
                int id = p*256 + tid; int m = id >> 4, kq = id & 15;
                union { u16 h[4]; uint2 v; } u;
                u.h[0] = f2bf(af[p].x); u.h[1] = f2bf(af[p].y);
                u.h[2] = f2bf(af[p].z); u.h[3] = f2bf(af[p].w);
                *(uint2*)&As[m][kq*4] = u.v;
            }
        }
        {
            union { u16 h[8]; short8 v; } w8;
            #pragma unroll
            for (int p = 0; p < 8; p++) w8.h[p] = f2bf(wf[p]);
            *(short8*)&Ws[wn][wk*8] = w8.v;
        }
        __syncthreads();
        // prefetch next K-slice (overlaps with MFMAs below)
        if (kt < 11) {
            int k0 = (kt + 1) * 64;
            if (ABF16) {
                #pragma unroll
                for (int p = 0; p < 2; p++) {
                    int id = p*256 + tid; int m = id >> 3, kq = id & 7;
                    ab[p] = *(const short8*)((const u16*)A + (size_t)(m0+m)*D_ + k0 + kq*8);
                }
            } else {
                #pragma unroll
                for (int p = 0; p < 4; p++) {
                    int id = p*256 + tid; int m = id >> 4, kq = id & 15;
                    int row = m0 + m; if (row >= Mvalid) row = Mvalid - 1;
                    af[p] = *(const float4*)((const float*)A + (size_t)row*D_ + k0 + kq*4);
                }
            }
            #pragma unroll
            for (int p = 0; p < 8; p++) wf[p] = W[(size_t)(k0 + wk*8 + p)*D_ + n0 + wn];
        }
        #pragma unroll
        for (int ks = 0; ks < 2; ks++) {
            short8 a = *(const short8*)&As[wave*16 + qm][ks*32 + k8];
            #pragma unroll
            for (int bt = 0; bt < 2; bt++) {
                short8 b = *(const short8*)&Ws[bt*16 + qm][ks*32 + k8];
                acc[bt] = __builtin_amdgcn_mfma_f32_16x16x32_bf16(a, b, acc[bt], 0,0,0);
            }
        }
    }

    #pragma unroll
    for (int bt = 0; bt < 2; bt++) {
        int c = n0 + bt*16 + qm;
        #pragma unroll
        for (int g = 0; g < 4; g++) {
            int row = m0 + wave*16 + quad*4 + g;
            if (EPI == 0) {
                if (row < Mvalid)
                    outb[((size_t)(c >> 6)*T_ + row)*DH + (c & 63)] = f2bf(acc[bt][g]);
            } else {
                outf[(size_t)row*D_ + c] = acc[bt][g] + bias[c] + resid[(size_t)row*D_ + c];
            }
        }
    }
}

// ---------------- Kernel C: MFMA fused rel-attention v3 ----------------
// SC (content) + PSC (pos, plain stores) -> 2 barriers total. XCD-swizzled blocks.
__global__ __launch_bounds__(256, 2) void attn_kernel(
    const u16* __restrict__ qq,
    const u16* __restrict__ kk, const u16* __restrict__ vt,
    const u16* __restrict__ R,
    const float* __restrict__ rwb, const float* __restrict__ rrb,
    u16* __restrict__ av)
{
    __shared__ char smem[64*1024];
    u16* SC  = (u16*)smem;            // [16][1024] content scores -> probs
    u16* PSC = (u16*)(smem + 32768);  // [16][1024] pos scores
    int tid  = threadIdx.x;
    int wave = tid >> 6, lane = tid & 63;
    int qm   = lane & 15;
    int quad = lane >> 4;
    int k8   = quad * 8;
    // XCD swizzle: all 64 i-tiles of a head land on one XCD (blk%8 heuristic)
    int blkid = blockIdx.x;
    int xcd = blkid & 7;
    int sl  = blkid >> 3;
    int it  = sl & 63;
    int seg = sl >> 6;                // 0..2
    int bn  = xcd + 8*seg;            // 0..23, bijective
    int b = bn / H_, n = bn % H_;
    int i0 = it * 16;
    size_t hbase = (size_t)bn * S_ * DH;

    // ---- Q fragments ----
    short8 qcf[2], qpf[2];
    #pragma unroll
    for (int s = 0; s < 2; s++) {
        const u16* qptr = qq + hbase + (size_t)(i0 + qm)*DH + s*32 + k8;
        const float* rwp = rwb + n*DH + s*32 + k8;
        const float* rrp = rrb + n*DH + s*32 + k8;
        #pragma unroll
        for (int j = 0; j < 8; j++) {
            float qv = bf2f(qptr[j]);
            qcf[s][j] = (short)f2bf(qv + rwp[j]*SCALEF);
            qpf[s][j] = (short)f2bf(qv + rrp[j]*SCALEF);
        }
    }

    // ---- Phase 1: content scores -> SC ----
    #pragma unroll 4
    for (int tjt = 0; tjt < 16; tjt++) {
        int j0 = (wave*16 + tjt) * 16;
        const u16* kp = kk + hbase + (size_t)(j0 + qm)*DH + k8;
        short8 b0 = *(const short8*)(kp);
        short8 b1 = *(const short8*)(kp + 32);
        floatx4 acc = {0.f,0.f,0.f,0.f};
        acc = __builtin_amdgcn_mfma_f32_16x16x32_bf16(qcf[0], b0, acc, 0,0,0);
        acc = __builtin_amdgcn_mfma_f32_16x16x32_bf16(qcf[1], b1, acc, 0,0,0);
        #pragma unroll
        for (int g = 0; g < 4; g++)
            SC[(quad*4 + g)*1024 + j0 + qm] = f2bf(acc[g]);
    }

    // ---- Phase 2: pos scores -> PSC (plain stores; unique (row,j) targets) ----
    int ubase = 1008 - i0;
    #pragma unroll 4
    for (int mm = 0; mm < 16; mm++) {
        int m = mm*4 + wave;
        int uu = ubase + m*16 + qm;
        int ur = (uu <= 2046) ? uu : 2046;
        const u16* rp = R + ((size_t)n*T_ + ur)*DH + k8;
        short8 b0 = *(const short8*)(rp);
        short8 b1 = *(const short8*)(rp + 32);
        floatx4 acc = {0.f,0.f,0.f,0.f};
        acc = __builtin_amdgcn_mfma_f32_16x16x32_bf16(qpf[0], b0, acc, 0,0,0);
        acc = __builtin_amdgcn_mfma_f32_16x16x32_bf16(qpf[1], b1, acc, 0,0,0);
        #pragma unroll
        for (int g = 0; g < 4; g++) {
            int row = quad*4 + g;
            int j = uu + i0 + row - 1024;
            if (j >= 0 && j < S_ && uu <= 2046)
                PSC[row*1024 + j] = f2bf(acc[g]);
        }
    }
    if (wave == 0) {   // tile 64 (the 65th)
        int uu = ubase + 64*16 + qm;
        int ur = (uu <= 2046) ? uu : 2046;
        const u16* rp = R + ((size_t)n*T_ + ur)*DH + k8;
        short8 b0 = *(const short8*)(rp);
        short8 b1 = *(const short8*)(rp + 32);
        floatx4 acc = {0.f,0.f,0.f,0.f};
        acc = __builtin_amdgcn_mfma_f32_16x16x32_bf16(qpf[0], b0, acc, 0,0,0);
        acc = __builtin_amdgcn_mfma_f32_16x16x32_bf16(qpf[1], b1, acc, 0,0,0);
        #pragma unroll
        for (int g = 0; g < 4; g++) {
            int row = quad*4 + g;
            int j = uu + i0 + row - 1024;
            if (j >= 0 && j < S_ && uu <= 2046)
                PSC[row*1024 + j] = f2bf(acc[g]);
        }
    }
    // HF rel_shift wraparound: (i=0, j=1023) uses qp row 1, R row 0 (plain store)
    if (i0 == 0 && tid == 0) {
        float sdot = 0.f;
        const u16* r0p = R + (size_t)n*T_*DH;
        const u16* q1p = qq + hbase + DH;
        for (int d = 0; d < DH; d++)
            sdot += (bf2f(q1p[d]) + rrb[n*DH + d]*SCALEF) * bf2f(r0p[d]);
        PSC[1023] = f2bf(sdot);
    }
    __syncthreads();

    // ---- Phase 3: softmax (SC + PSC); probs -> SC region, XOR chunk swizzle ----
    for (int rr = 0; rr < 4; rr++) {
        int r = wave*4 + rr;
        float p[16];
        float mx = -1e30f;
        #pragma unroll
        for (int q = 0; q < 16; q++) {
            int j = q*64 + lane;
            p[q] = bf2f(SC[r*1024 + j]) + bf2f(PSC[r*1024 + j]);
            mx = fmaxf(mx, p[q]);
        }
        #pragma unroll
        for (int off = 32; off; off >>= 1) mx = fmaxf(mx, __shfl_xor(mx, off));
        float ssum = 0.f;
        #pragma unroll
        for (int q = 0; q < 16; q++) { p[q] = __expf(p[q] - mx); ssum += p[q]; }
        #pragma unroll
        for (int off = 32; off; off >>= 1) ssum += __shfl_xor(ssum, off);
        float inv = 1.0f / ssum;
        int swz = r & 7;
        #pragma unroll
        for (int q = 0; q < 16; q++) {
            int j = q*64 + lane;
            SC[r*1024 + (((j >> 3) ^ swz) << 3) + (j & 7)] = f2bf(p[q]*inv);
        }
    }
    __syncthreads();

    // ---- Phase 4: PV; 4 accumulators to break the MFMA chain ----
    int d0 = wave*16;
    const u16* vbase = vt + ((size_t)bn*DH + d0 + qm)*S_;
    floatx4 o[4];
    #pragma unroll
    for (int t = 0; t < 4; t++) o[t] = (floatx4){0.f,0.f,0.f,0.f};
    int aswz = qm & 7;
    #pragma unroll 8
    for (int kt = 0; kt < 32; kt++) {
        int chunk = (kt*4 + quad) ^ aswz;
        short8 a = *(const short8*)(SC + qm*1024 + (chunk << 3));
        short8 bfr = *(const short8*)(vbase + kt*32 + k8);
        o[kt & 3] = __builtin_amdgcn_mfma_f32_16x16x32_bf16(a, bfr, o[kt & 3], 0,0,0);
    }
    floatx4 os = (o[0] + o[1]) + (o[2] + o[3]);
    #pragma unroll
    for (int g = 0; g < 4; g++) {
        int row = quad*4 + g;
        av[((size_t)(b*S_) + i0 + row)*D_ + n*DH + d0 + qm] = f2bf(os[g]);
    }
}

// ---------------- Kernel E: in-place LayerNorm (float4 I/O) ----------------
__global__ __launch_bounds__(256) void ln_kernel(
    const float* __restrict__ gamma, const float* __restrict__ beta,
    float* out)
{
    __shared__ float hb[8][D_];
    int tid = threadIdx.x;
    int rowg0 = blockIdx.x * 8;
    #pragma unroll
    for (int p = 0; p < 6; p++) {
        int id = p*256 + tid;            // 0..1535
        int r = id / 192, e4 = id % 192;
        *(float4*)&hb[r][e4*4] = *(const float4*)&out[(size_t)(rowg0 + r)*D_ + e4*4];
    }
    __syncthreads();
    int wave = tid >> 6, lane = tid & 63;
    for (int rr = 0; rr < 2; rr++) {
        int r = wave*2 + rr;
        float s = 0.f;
        #pragma unroll
        for (int kq = 0; kq < 12; kq++) s += hb[r][lane + kq*64];
        #pragma unroll
        for (int off = 32; off; off >>= 1) s += __shfl_xor(s, off);
        float mu = s * (1.0f/768.0f);
        float vsum = 0.f;
        #pragma unroll
        for (int kq = 0; kq < 12; kq++) { float d = hb[r][lane + kq*64] - mu; vsum += d*d; }
        #pragma unroll
        for (int off = 32; off; off >>= 1) vsum += __shfl_xor(vsum, off);
        float rstd = rsqrtf(vsum * (1.0f/768.0f) + 1e-9f);
        #pragma unroll
        for (int kq = 0; kq < 3; kq++) {
            int c4 = lane + kq*64;
            float4 g4 = *(const float4*)&gamma[c4*4];
            float4 b4 = *(const float4*)&beta[c4*4];
            float4 h4 = *(const float4*)&hb[r][c4*4];
            float4 o4;
            o4.x = (h4.x - mu)*rstd*g4.x + b4.x;
            o4.y = (h4.y - mu)*rstd*g4.y + b4.y;
            o4.z = (h4.z - mu)*rstd*g4.z + b4.z;
            o4.w = (h4.w - mu)*rstd*g4.w + b4.w;
            *(float4*)&out[(size_t)(rowg0 + r)*D_ + c4*4] = o4;
        }
    }
}

extern "C" void kernel_launch(void* const* d_in, const int* in_sizes, int n_in,
                              void* d_out, int out_size, void* d_ws, size_t ws_size,
                              hipStream_t stream) {
    const float* query = (const float*)d_in[0];
    const float* pe    = (const float*)d_in[1];
    const float* Wq    = (const float*)d_in[2];
    const float* Wk    = (const float*)d_in[3];
    const float* bk    = (const float*)d_in[4];
    const float* Wv    = (const float*)d_in[5];
    const float* bv    = (const float*)d_in[6];
    const float* rk    = (const float*)d_in[7];
    const float* rwb   = (const float*)d_in[8];
    const float* rrb   = (const float*)d_in[9];
    const float* Wo    = (const float*)d_in[10];
    const float* bo    = (const float*)d_in[11];
    const float* gamma = (const float*)d_in[12];
    const float* beta  = (const float*)d_in[13];
    float* out = (float*)d_out;

    u16* ws = (u16*)d_ws;
    const size_t SEG = (size_t)B_*H_*S_*DH;       // 1,572,864 elems (3 MB bf16)
    u16* qq = ws;             // [bn][s][d]
    u16* kk = qq + SEG;       // [bn][s][d]
    u16* vt = kk + SEG;       // [bn][d][s]  (transposed V)
    u16* R  = vt + SEG;       // [n][2047][d]
    u16* av = R + SEG;        // [b*S+s][n*64+d] bf16 attn_vec

    proj_kernel<<<dim3(32,12), 256, 0, stream>>>(query, Wq, Wk, Wv, bk, bv, qq, kk, vt);
    gemm_kernel<0,false><<<dim3(32,24), 256, 0, stream>>>(pe, rk, nullptr, nullptr, R, nullptr, T_);
    attn_kernel<<<1536, 256, 0, stream>>>(qq, kk, vt, R, rwb, rrb, av);
    gemm_kernel<1,true><<<dim3(32,24), 256, 0, stream>>>(av, Wo, bo, query, nullptr, out, B_*S_);
    ln_kernel<<<256, 256, 0, stream>>>(gamma, beta, out);
}

// Round 9
// 207.186 us; speedup vs baseline: 4.2685x; 1.0114x over previous
//
#include <hip/hip_runtime.h>
#include <stdint.h>

#define B_ 2
#define S_ 1024
#define D_ 768
#define H_ 12
#define DH 64
#define G_ 4
#define DG 192
#define T_ 2047
#define SCALEF 0.125f

typedef unsigned short u16;
typedef unsigned int u32;
typedef __attribute__((ext_vector_type(8))) short short8;
typedef __attribute__((ext_vector_type(4))) float floatx4;

__device__ __forceinline__ float uas(u32 x){ union { u32 i; float f; } v; v.i = x; return v.f; }
__device__ __forceinline__ float bf2f(u16 u){ return uas(((u32)u) << 16); }
__device__ __forceinline__ u16 f2bf(float f){
    union { float f; u32 i; } v; v.f = f;
    u32 x = v.i;
    u32 r = (x + 0x7fffu + ((x >> 16) & 1u)) >> 16;  // RNE
    return (u16)r;
}

// ---------------- Kernel A: MFMA grouped q/k/v projections ----------------
__global__ __launch_bounds__(256) void proj_kernel(
    const float* __restrict__ query,
    const float* __restrict__ Wq, const float* __restrict__ Wk, const float* __restrict__ Wv,
    const float* __restrict__ bk, const float* __restrict__ bv,
    u16* __restrict__ qq, u16* __restrict__ ko, u16* __restrict__ vt)
{
    __shared__ u16 As[64][40];
    __shared__ u16 Ws[3][64][38];
    int tid  = threadIdx.x;
    int wave = tid >> 6, lane = tid & 63;
    int qm   = lane & 15;
    int quad = lane >> 4;
    int k8   = quad * 8;
    int m0 = blockIdx.x * 64;
    int g  = blockIdx.y / 3;
    int n0 = (blockIdx.y % 3) * 64;

    const float* Wm[3] = { Wq, Wk, Wv };

    floatx4 acc[3][4];
    #pragma unroll
    for (int md = 0; md < 3; md++)
        #pragma unroll
        for (int bt = 0; bt < 4; bt++) acc[md][bt] = (floatx4){0.f,0.f,0.f,0.f};

    for (int kt = 0; kt < 6; kt++) {
        int k0 = kt * 32;
        #pragma unroll
        for (int p = 0; p < 8; p++) {
            int idx = p*256 + tid;
            int m = idx >> 5, k = idx & 31;
            As[m][k] = f2bf(query[(size_t)(m0 + m)*D_ + g*DG + k0 + k]);
        }
        #pragma unroll
        for (int md = 0; md < 3; md++) {
            const float* W = Wm[md] + (size_t)g*DG*DG;
            #pragma unroll
            for (int p = 0; p < 8; p++) {
                int k = p*4 + (tid >> 6);
                int n = tid & 63;
                Ws[md][n][k] = f2bf(W[(size_t)(k0 + k)*DG + n0 + n]);
            }
        }
        __syncthreads();
        short8 a = *(const short8*)&As[wave*16 + qm][k8];
        #pragma unroll
        for (int md = 0; md < 3; md++) {
            #pragma unroll
            for (int bt = 0; bt < 4; bt++) {
                short8 b = *(const short8*)&Ws[md][bt*16 + qm][k8];
                acc[md][bt] = __builtin_amdgcn_mfma_f32_16x16x32_bf16(a, b, acc[md][bt], 0,0,0);
            }
        }
        __syncthreads();
    }

    int rowbase = m0 + wave*16 + quad*4;
    int b  = rowbase >> 10;
    int s0 = rowbase & 1023;
    #pragma unroll
    for (int bt = 0; bt < 4; bt++) {
        int c = g*DG + n0 + bt*16 + qm;
        int n = c >> 6, d = c & 63;
        int bn = b*H_ + n;
        float bkv = bk[c], bvv = bv[c];
        #pragma unroll
        for (int gg = 0; gg < 4; gg++) {
            size_t o = ((size_t)bn*S_ + s0 + gg)*DH + d;
            qq[o] = f2bf(acc[0][bt][gg]*SCALEF);
            ko[o] = f2bf(acc[1][bt][gg] + bkv);
        }
        union { u16 h[4]; uint2 v; } vv;
        #pragma unroll
        for (int gg = 0; gg < 4; gg++) vv.h[gg] = f2bf(acc[2][bt][gg] + bvv);
        *(uint2*)(vt + ((size_t)bn*DH + d)*S_ + s0) = vv.v;
    }
}

// ---------------- Shared MFMA GEMM v2: BM=64 BN=32 BK=64, reg-prefetch pipeline ----
template<int EPI, bool ABF16>
__global__ __launch_bounds__(256) void gemm_kernel(
    const void* __restrict__ A, const float* __restrict__ W,
    const float* __restrict__ bias, const float* __restrict__ resid,
    u16* __restrict__ outb, float* __restrict__ outf, int Mvalid)
{
    __shared__ u16 As[64][72];
    __shared__ u16 Ws[32][72];
    int tid  = threadIdx.x;
    int wave = tid >> 6, lane = tid & 63;
    int qm   = lane & 15;
    int quad = lane >> 4;
    int k8   = quad * 8;
    int m0 = blockIdx.x * 64;
    int n0 = blockIdx.y * 32;
    int wn = tid & 31, wk = tid >> 5;

    float4 af[4]; short8 ab[2]; float wf[8];
    floatx4 acc[2];
    acc[0] = (floatx4){0.f,0.f,0.f,0.f};
    acc[1] = (floatx4){0.f,0.f,0.f,0.f};

    if (ABF16) {
        #pragma unroll
        for (int p = 0; p < 2; p++) {
            int id = p*256 + tid; int m = id >> 3, kq = id & 7;
            ab[p] = *(const short8*)((const u16*)A + (size_t)(m0+m)*D_ + kq*8);
        }
    } else {
        #pragma unroll
        for (int p = 0; p < 4; p++) {
            int id = p*256 + tid; int m = id >> 4, kq = id & 15;
            int row = m0 + m; if (row >= Mvalid) row = Mvalid - 1;
            af[p] = *(const float4*)((const float*)A + (size_t)row*D_ + kq*4);
        }
    }
    #pragma unroll
    for (int p = 0; p < 8; p++) wf[p] = W[(size_t)(wk*8 + p)*D_ + n0 + wn];

    for (int kt = 0; kt < 12; kt++) {
        __syncthreads();
        if (ABF16) {
            #pragma unroll
            for (int p = 0; p < 2; p++) {
                int id = p*256 + tid; int m = id >> 3, kq = id & 7;
                *(short8*)&As[m][kq*8] = ab[p];
            }
        } else {
            #pragma unroll
            for (int p = 0; p < 4; p++) {
                int id = p*256 + tid; int m = id >> 4, kq = id & 15;
                union { u16 h[4]; uint2 v; } u;
                u.h[0] = f2bf(af[p].x); u.h[1] = f2bf(af[p].y);
                u.h[2] = f2bf(af[p].z); u.h[3] = f2bf(af[p].w);
                *(uint2*)&As[m][kq*4] = u.v;
            }
        }
        {
            union { u16 h[8]; short8 v; } w8;
            #pragma unroll
            for (int p = 0; p < 8; p++) w8.h[p] = f2bf(wf[p]);
            *(short8*)&Ws[wn][wk*8] = w8.v;
        }
        __syncthreads();
        if (kt < 11) {
            int k0 = (kt + 1) * 64;
            if (ABF16) {
                #pragma unroll
                for (int p = 0; p < 2; p++) {
                    int id = p*256 + tid; int m = id >> 3, kq = id & 7;
                    ab[p] = *(const short8*)((const u16*)A + (size_t)(m0+m)*D_ + k0 + kq*8);
                }
            } else {
                #pragma unroll
                for (int p = 0; p < 4; p++) {
                    int id = p*256 + tid; int m = id >> 4, kq = id & 15;
                    int row = m0 + m; if (row >= Mvalid) row = Mvalid - 1;
                    af[p] = *(const float4*)((const float*)A + (size_t)row*D_ + k0 + kq*4);
                }
            }
            #pragma unroll
            for (int p = 0; p < 8; p++) wf[p] = W[(size_t)(k0 + wk*8 + p)*D_ + n0 + wn];
        }
        #pragma unroll
        for (int ks = 0; ks < 2; ks++) {
            short8 a = *(const short8*)&As[wave*16 + qm][ks*32 + k8];
            #pragma unroll
            for (int bt = 0; bt < 2; bt++) {
                short8 b = *(const short8*)&Ws[bt*16 + qm][ks*32 + k8];
                acc[bt] = __builtin_amdgcn_mfma_f32_16x16x32_bf16(a, b, acc[bt], 0,0,0);
            }
        }
    }

    #pragma unroll
    for (int bt = 0; bt < 2; bt++) {
        int c = n0 + bt*16 + qm;
        #pragma unroll
        for (int g = 0; g < 4; g++) {
            int row = m0 + wave*16 + quad*4 + g;
            if (EPI == 0) {
                if (row < Mvalid)
                    outb[((size_t)(c >> 6)*T_ + row)*DH + (c & 63)] = f2bf(acc[bt][g]);
            } else {
                outf[(size_t)row*D_ + c] = acc[bt][g] + bias[c] + resid[(size_t)row*D_ + c];
            }
        }
    }
}

// ---------------- Kernel C: MFMA fused rel-attention v4 ----------------
// Ring-buffer 8-deep load prefetch in phases 1/2/4; vectorized softmax LDS I/O.
__global__ __launch_bounds__(256, 2) void attn_kernel(
    const u16* __restrict__ qq,
    const u16* __restrict__ kk, const u16* __restrict__ vt,
    const u16* __restrict__ R,
    const float* __restrict__ rwb, const float* __restrict__ rrb,
    u16* __restrict__ av)
{
    __shared__ char smem[64*1024];
    u16* SC  = (u16*)smem;            // [16][1024] content scores -> probs
    u16* PSC = (u16*)(smem + 32768);  // [16][1024] pos scores
    int tid  = threadIdx.x;
    int wave = tid >> 6, lane = tid & 63;
    int qm   = lane & 15;
    int quad = lane >> 4;
    int k8   = quad * 8;
    // XCD swizzle: all 64 i-tiles of a head land on one XCD
    int blkid = blockIdx.x;
    int xcd = blkid & 7;
    int sl  = blkid >> 3;
    int it  = sl & 63;
    int seg = sl >> 6;                // 0..2
    int bn  = xcd + 8*seg;            // 0..23, bijective
    int b = bn / H_, n = bn % H_;
    int i0 = it * 16;
    size_t hbase = (size_t)bn * S_ * DH;

    // ---- Q fragments ----
    short8 qcf[2], qpf[2];
    #pragma unroll
    for (int s = 0; s < 2; s++) {
        const u16* qptr = qq + hbase + (size_t)(i0 + qm)*DH + s*32 + k8;
        const float* rwp = rwb + n*DH + s*32 + k8;
        const float* rrp = rrb + n*DH + s*32 + k8;
        #pragma unroll
        for (int j = 0; j < 8; j++) {
            float qv = bf2f(qptr[j]);
            qcf[s][j] = (short)f2bf(qv + rwp[j]*SCALEF);
            qpf[s][j] = (short)f2bf(qv + rrp[j]*SCALEF);
        }
    }

    // ---- Phase 1: content scores -> SC, ring prefetch depth 8 ----
    {
        const u16* kbb = kk + hbase + (size_t)qm*DH + k8;
        short8 rb[8][2];
        #pragma unroll
        for (int t = 0; t < 8; t++) {
            const u16* kp = kbb + (size_t)((wave*16 + t)*16)*DH;
            rb[t][0] = *(const short8*)(kp);
            rb[t][1] = *(const short8*)(kp + 32);
        }
        #pragma unroll
        for (int t = 0; t < 16; t++) {
            short8 b0 = rb[t & 7][0], b1 = rb[t & 7][1];
            if (t < 8) {
                const u16* kp = kbb + (size_t)((wave*16 + t + 8)*16)*DH;
                rb[t & 7][0] = *(const short8*)(kp);
                rb[t & 7][1] = *(const short8*)(kp + 32);
            }
            floatx4 acc = {0.f,0.f,0.f,0.f};
            acc = __builtin_amdgcn_mfma_f32_16x16x32_bf16(qcf[0], b0, acc, 0,0,0);
            acc = __builtin_amdgcn_mfma_f32_16x16x32_bf16(qcf[1], b1, acc, 0,0,0);
            int j0 = (wave*16 + t) * 16;
            #pragma unroll
            for (int g = 0; g < 4; g++)
                SC[(quad*4 + g)*1024 + j0 + qm] = f2bf(acc[g]);
        }
    }

    // ---- Phase 2: pos scores -> PSC (plain stores; unique targets), ring prefetch ----
    int ubase = 1008 - i0;
    {
        const u16* rbb = R + (size_t)n*T_*DH + k8;
        short8 rb[8][2];
        int us[8];
        #pragma unroll
        for (int t = 0; t < 8; t++) {
            int m = t*4 + wave;
            int uu = ubase + m*16 + qm;
            int ur = (uu <= 2046) ? uu : 2046;
            us[t] = uu;
            const u16* rp = rbb + (size_t)ur*DH;
            rb[t][0] = *(const short8*)(rp);
            rb[t][1] = *(const short8*)(rp + 32);
        }
        #pragma unroll
        for (int t = 0; t < 16; t++) {
            short8 b0 = rb[t & 7][0], b1 = rb[t & 7][1];
            int uu = us[t & 7];
            if (t < 8) {
                int m2 = (t + 8)*4 + wave;
                int uu2 = ubase + m2*16 + qm;
                int ur2 = (uu2 <= 2046) ? uu2 : 2046;
                us[t & 7] = uu2;
                const u16* rp = rbb + (size_t)ur2*DH;
                rb[t & 7][0] = *(const short8*)(rp);
                rb[t & 7][1] = *(const short8*)(rp + 32);
            }
            floatx4 acc = {0.f,0.f,0.f,0.f};
            acc = __builtin_amdgcn_mfma_f32_16x16x32_bf16(qpf[0], b0, acc, 0,0,0);
            acc = __builtin_amdgcn_mfma_f32_16x16x32_bf16(qpf[1], b1, acc, 0,0,0);
            #pragma unroll
            for (int g = 0; g < 4; g++) {
                int row = quad*4 + g;
                int j = uu + i0 + row - 1024;
                if (j >= 0 && j < S_ && uu <= 2046)
                    PSC[row*1024 + j] = f2bf(acc[g]);
            }
        }
    }
    if (wave == 0) {   // tile 64 (the 65th)
        int uu = ubase + 64*16 + qm;
        int ur = (uu <= 2046) ? uu : 2046;
        const u16* rp = R + ((size_t)n*T_ + ur)*DH + k8;
        short8 b0 = *(const short8*)(rp);
        short8 b1 = *(const short8*)(rp + 32);
        floatx4 acc = {0.f,0.f,0.f,0.f};
        acc = __builtin_amdgcn_mfma_f32_16x16x32_bf16(qpf[0], b0, acc, 0,0,0);
        acc = __builtin_amdgcn_mfma_f32_16x16x32_bf16(qpf[1], b1, acc, 0,0,0);
        #pragma unroll
        for (int g = 0; g < 4; g++) {
            int row = quad*4 + g;
            int j = uu + i0 + row - 1024;
            if (j >= 0 && j < S_ && uu <= 2046)
                PSC[row*1024 + j] = f2bf(acc[g]);
        }
    }
    // HF rel_shift wraparound: (i=0, j=1023) uses qp row 1, R row 0 (plain store)
    if (i0 == 0 && tid == 0) {
        float sdot = 0.f;
        const u16* r0p = R + (size_t)n*T_*DH;
        const u16* q1p = qq + hbase + DH;
        for (int d = 0; d < DH; d++)
            sdot += (bf2f(q1p[d]) + rrb[n*DH + d]*SCALEF) * bf2f(r0p[d]);
        PSC[1023] = f2bf(sdot);
    }
    __syncthreads();

    // ---- Phase 3: softmax (SC + PSC), vectorized b128 I/O; probs -> SC swizzled ----
    // lane owns j in [lane*16, lane*16+16)
    for (int rr = 0; rr < 4; rr++) {
        int r = wave*4 + rr;
        short8 c0 = *(const short8*)(SC  + r*1024 + lane*16);
        short8 c1 = *(const short8*)(SC  + r*1024 + lane*16 + 8);
        short8 p0 = *(const short8*)(PSC + r*1024 + lane*16);
        short8 p1 = *(const short8*)(PSC + r*1024 + lane*16 + 8);
        float p[16];
        float mx = -1e30f;
        #pragma unroll
        for (int q = 0; q < 8; q++) {
            p[q]   = bf2f((u16)c0[q]) + bf2f((u16)p0[q]);
            p[q+8] = bf2f((u16)c1[q]) + bf2f((u16)p1[q]);
        }
        #pragma unroll
        for (int q = 0; q < 16; q++) mx = fmaxf(mx, p[q]);
        #pragma unroll
        for (int off = 32; off; off >>= 1) mx = fmaxf(mx, __shfl_xor(mx, off));
        float ssum = 0.f;
        #pragma unroll
        for (int q = 0; q < 16; q++) { p[q] = __expf(p[q] - mx); ssum += p[q]; }
        #pragma unroll
        for (int off = 32; off; off >>= 1) ssum += __shfl_xor(ssum, off);
        float inv = 1.0f / ssum;
        int swz = r & 7;
        union { u16 h[8]; short8 v; } w0, w1;
        #pragma unroll
        for (int q = 0; q < 8; q++) {
            w0.h[q] = f2bf(p[q]*inv);
            w1.h[q] = f2bf(p[q+8]*inv);
        }
        *(short8*)(SC + r*1024 + (((2*lane)   ^ swz) << 3)) = w0.v;
        *(short8*)(SC + r*1024 + (((2*lane+1) ^ swz) << 3)) = w1.v;
    }

    // ---- Phase 4 preload (independent of LDS) ----
    int d0 = wave*16;
    const u16* vbase = vt + ((size_t)bn*DH + d0 + qm)*S_;
    short8 vb[8];
    #pragma unroll
    for (int t = 0; t < 8; t++) vb[t] = *(const short8*)(vbase + t*32 + k8);
    __syncthreads();

    // ---- Phase 4: PV; ring prefetch + 4 accumulators ----
    floatx4 o[4];
    #pragma unroll
    for (int t = 0; t < 4; t++) o[t] = (floatx4){0.f,0.f,0.f,0.f};
    int aswz = qm & 7;
    #pragma unroll
    for (int kt = 0; kt < 32; kt++) {
        short8 bfr = vb[kt & 7];
        if (kt < 24) vb[kt & 7] = *(const short8*)(vbase + (kt + 8)*32 + k8);
        int chunk = (kt*4 + quad) ^ aswz;
        short8 a = *(const short8*)(SC + qm*1024 + (chunk << 3));
        o[kt & 3] = __builtin_amdgcn_mfma_f32_16x16x32_bf16(a, bfr, o[kt & 3], 0,0,0);
    }
    floatx4 os = (o[0] + o[1]) + (o[2] + o[3]);
    #pragma unroll
    for (int g = 0; g < 4; g++) {
        int row = quad*4 + g;
        av[((size_t)(b*S_) + i0 + row)*D_ + n*DH + d0 + qm] = f2bf(os[g]);
    }
}

// ---------------- Kernel E: in-place LayerNorm (float4 I/O) ----------------
__global__ __launch_bounds__(256) void ln_kernel(
    const float* __restrict__ gamma, const float* __restrict__ beta,
    float* out)
{
    __shared__ float hb[8][D_];
    int tid = threadIdx.x;
    int rowg0 = blockIdx.x * 8;
    #pragma unroll
    for (int p = 0; p < 6; p++) {
        int id = p*256 + tid;
        int r = id / 192, e4 = id % 192;
        *(float4*)&hb[r][e4*4] = *(const float4*)&out[(size_t)(rowg0 + r)*D_ + e4*4];
    }
    __syncthreads();
    int wave = tid >> 6, lane = tid & 63;
    for (int rr = 0; rr < 2; rr++) {
        int r = wave*2 + rr;
        float s = 0.f;
        #pragma unroll
        for (int kq = 0; kq < 12; kq++) s += hb[r][lane + kq*64];
        #pragma unroll
        for (int off = 32; off; off >>= 1) s += __shfl_xor(s, off);
        float mu = s * (1.0f/768.0f);
        float vsum = 0.f;
        #pragma unroll
        for (int kq = 0; kq < 12; kq++) { float d = hb[r][lane + kq*64] - mu; vsum += d*d; }
        #pragma unroll
        for (int off = 32; off; off >>= 1) vsum += __shfl_xor(vsum, off);
        float rstd = rsqrtf(vsum * (1.0f/768.0f) + 1e-9f);
        #pragma unroll
        for (int kq = 0; kq < 3; kq++) {
            int c4 = lane + kq*64;
            float4 g4 = *(const float4*)&gamma[c4*4];
            float4 b4 = *(const float4*)&beta[c4*4];
            float4 h4 = *(const float4*)&hb[r][c4*4];
            float4 o4;
            o4.x = (h4.x - mu)*rstd*g4.x + b4.x;
            o4.y = (h4.y - mu)*rstd*g4.y + b4.y;
            o4.z = (h4.z - mu)*rstd*g4.z + b4.z;
            o4.w = (h4.w - mu)*rstd*g4.w + b4.w;
            *(float4*)&out[(size_t)(rowg0 + r)*D_ + c4*4] = o4;
        }
    }
}

extern "C" void kernel_launch(void* const* d_in, const int* in_sizes, int n_in,
                              void* d_out, int out_size, void* d_ws, size_t ws_size,
                              hipStream_t stream) {
    const float* query = (const float*)d_in[0];
    const float* pe    = (const float*)d_in[1];
    const float* Wq    = (const float*)d_in[2];
    const float* Wk    = (const float*)d_in[3];
    const float* bk    = (const float*)d_in[4];
    const float* Wv    = (const float*)d_in[5];
    const float* bv    = (const float*)d_in[6];
    const float* rk    = (const float*)d_in[7];
    const float* rwb   = (const float*)d_in[8];
    const float* rrb   = (const float*)d_in[9];
    const float* Wo    = (const float*)d_in[10];
    const float* bo    = (const float*)d_in[11];
    const float* gamma = (const float*)d_in[12];
    const float* beta  = (const float*)d_in[13];
    float* out = (float*)d_out;

    u16* ws = (u16*)d_ws;
    const size_t SEG = (size_t)B_*H_*S_*DH;       // 1,572,864 elems (3 MB bf16)
    u16* qq = ws;             // [bn][s][d]
    u16* kk = qq + SEG;       // [bn][s][d]
    u16* vt = kk + SEG;       // [bn][d][s]  (transposed V)
    u16* R  = vt + SEG;       // [n][2047][d]
    u16* av = R + SEG;        // [b*S+s][n*64+d] bf16 attn_vec

    proj_kernel<<<dim3(32,12), 256, 0, stream>>>(query, Wq, Wk, Wv, bk, bv, qq, kk, vt);
    gemm_kernel<0,false><<<dim3(32,24), 256, 0, stream>>>(pe, rk, nullptr, nullptr, R, nullptr, T_);
    attn_kernel<<<1536, 256, 0, stream>>>(qq, kk, vt, R, rwb, rrb, av);
    gemm_kernel<1,true><<<dim3(32,24), 256, 0, stream>>>(av, Wo, bo, query, nullptr, out, B_*S_);
    ln_kernel<<<256, 256, 0, stream>>>(gamma, beta, out);
}